// Round 1
// baseline (1150.780 us; speedup 1.0000x reference)
//
#include <hip/hip_runtime.h>

typedef unsigned short u16;
typedef unsigned int   u32;
typedef __attribute__((ext_vector_type(8))) short s8v;           // MFMA bf16 frag (8 bf16)
typedef __attribute__((ext_vector_type(8))) unsigned short us8;  // raw bf16x8 load
typedef __attribute__((ext_vector_type(4))) float f4v;           // MFMA acc frag

constexpr int BC  = 2;
constexpr int SL  = 4096;
constexpr int NH  = 12;
constexpr int HD  = 64;
constexpr int DM  = 768;
constexpr int WIN = 256;
constexpr int GLB = 64;
constexpr int QN  = 2304;   // q|k|v packed columns
constexpr float FOLD = 0.125f * 1.44269504088896f; // scale(1/sqrt(64)) * log2(e), folded into q
constexpr float NEGS = -1.0e9f;

__device__ __forceinline__ float b2f(u16 b){ return __uint_as_float(((u32)b) << 16); }
__device__ __forceinline__ u16 f2b(float f){
  u32 u = __float_as_uint(f);
  return (u16)((u + 0x7fffu + ((u >> 16) & 1u)) >> 16);  // RNE
}
__device__ __forceinline__ float wredsum(float v){
  #pragma unroll
  for (int o = 32; o > 0; o >>= 1) v += __shfl_xor(v, o, 64);
  return v;
}
__device__ __forceinline__ float wredmax(float v){
  #pragma unroll
  for (int o = 32; o > 0; o >>= 1) v = fmaxf(v, __shfl_xor(v, o, 64));
  return v;
}
__device__ __forceinline__ float sigf(float x){ return 1.f / (1.f + __expf(-x)); }

// ---------------------------------------------------------------- small packs
__global__ void transpose_pack(const float* __restrict__ src, u16* __restrict__ dst, int N){
  int e = blockIdx.x*256 + threadIdx.x;          // e = n*768 + k, dst is Bt[n][k]
  if (e >= N*768) return;
  int n = e / 768, k = e - n*768;
  dst[e] = f2b(src[(long)k*N + n]);
}

__global__ void pack_bias(const float* __restrict__ bq, const float* __restrict__ bk,
                          const float* __restrict__ bv, float* __restrict__ dst){
  int i = blockIdx.x*256 + threadIdx.x;
  if (i >= 2304) return;
  dst[i] = (i < 768) ? bq[i] : (i < 1536) ? bk[i-768] : bv[i-1536];
}

__global__ void embed_gather(const int* __restrict__ ids, const float* __restrict__ emb,
                             float* __restrict__ x, u16* __restrict__ xb){
  int e4 = blockIdx.x*256 + threadIdx.x;         // 8192 rows * 192 float4
  if (e4 >= 8192*192) return;
  int row = e4 / 192, d4 = e4 - row*192;
  int id = ids[row];
  float4 v = ((const float4*)(emb + (long)id*768))[d4];
  ((float4*)(x + (long)row*768))[d4] = v;
  u32 p0 = (u32)f2b(v.x) | ((u32)f2b(v.y) << 16);
  u32 p1 = (u32)f2b(v.z) | ((u32)f2b(v.w) << 16);
  ((u32*)(xb + (long)row*768))[d4*2]   = p0;
  ((u32*)(xb + (long)row*768))[d4*2+1] = p1;
}

__global__ void gather_hr(const int* __restrict__ hidx, const float* __restrict__ hn,
                          u16* __restrict__ hrb){
  int e = blockIdx.x*256 + threadIdx.x;          // 512 rows * 768
  if (e >= 512*768) return;
  int r = e / 768, d = e - r*768;
  int b = r >> 8;
  int idx = hidx[r];
  hrb[e] = f2b(hn[((long)(b*SL + idx))*768 + d]);
}

// ---------------------------------------------------------------- bf16 MFMA GEMM
// C[M,N] = A[M,K] @ Bt[N,K]^T (+bias/res, epilogue per MODE)
// MODE 0: outB = bf16(acc+bias)          (qkv)
// MODE 1: outF = acc+bias+res            (h = x + ctx@Wo + bo)
// MODE 2: outB = bf16(relu(acc+bias))    (t)
// MODE 3: outF = sigmoid(acc)            (cond, batched)
template<int MODE>
__global__ __launch_bounds__(256, 2)
void gemm_bt(const u16* __restrict__ A, const u16* __restrict__ Bt,
             const float* __restrict__ bias, const float* __restrict__ res,
             float* __restrict__ outF, u16* __restrict__ outB,
             int M, int N, int K, long sA, long sB, long sO)
{
  const int bz = blockIdx.z;
  A  += (long)bz * sA;
  Bt += (long)bz * sB;
  const int n0 = blockIdx.x * 128;
  const int m0 = blockIdx.y * 128;
  __shared__ u16 lsA[128*64];
  __shared__ u16 lsB[128*64];
  const int t = threadIdx.x;
  const int w = t >> 6, lane = t & 63;
  const int wr = w >> 1, wc = w & 1;
  const int fr = lane & 15, fq = lane >> 4;

  f4v acc[4][4];
  #pragma unroll
  for (int i=0;i<4;i++)
    #pragma unroll
    for (int j=0;j<4;j++) acc[i][j] = (f4v)0.f;

  for (int k0 = 0; k0 < K; k0 += 64){
    #pragma unroll
    for (int i=0;i<4;i++){
      int e = (w*4+i)*512 + lane*8;
      int row = e >> 6, col = e & 63;
      __builtin_amdgcn_global_load_lds(
        (const __attribute__((address_space(1))) void*)(A + (long)(m0+row)*K + (k0+col)),
        (__attribute__((address_space(3))) void*)(&lsA[(w*4+i)*512]), 16, 0, 0);
      __builtin_amdgcn_global_load_lds(
        (const __attribute__((address_space(1))) void*)(Bt + (long)(n0+row)*K + (k0+col)),
        (__attribute__((address_space(3))) void*)(&lsB[(w*4+i)*512]), 16, 0, 0);
    }
    __syncthreads();
    #pragma unroll
    for (int kk = 0; kk < 2; kk++){
      s8v af[4], bfv[4];
      #pragma unroll
      for (int mi=0;mi<4;mi++)
        af[mi] = *(const s8v*)&lsA[(wr*64 + mi*16 + fr)*64 + kk*32 + fq*8];
      #pragma unroll
      for (int ni=0;ni<4;ni++)
        bfv[ni] = *(const s8v*)&lsB[(wc*64 + ni*16 + fr)*64 + kk*32 + fq*8];
      #pragma unroll
      for (int mi=0;mi<4;mi++)
        #pragma unroll
        for (int ni=0;ni<4;ni++)
          acc[mi][ni] = __builtin_amdgcn_mfma_f32_16x16x32_bf16(af[mi], bfv[ni], acc[mi][ni], 0, 0, 0);
    }
    __syncthreads();
  }
  #pragma unroll
  for (int mi=0;mi<4;mi++){
    #pragma unroll
    for (int ni=0;ni<4;ni++){
      #pragma unroll
      for (int r=0;r<4;r++){
        int row = m0 + wr*64 + mi*16 + fq*4 + r;
        int col = n0 + wc*64 + ni*16 + fr;
        float v = acc[mi][ni][r];
        if constexpr (MODE == 0){
          v += bias[col];
          outB[(long)row*N + col] = f2b(v);
        } else if constexpr (MODE == 1){
          v += bias[col] + res[(long)row*N + col];
          outF[(long)row*N + col] = v;
        } else if constexpr (MODE == 2){
          v = fmaxf(v + bias[col], 0.f);
          outB[(long)row*N + col] = f2b(v);
        } else {
          (outF + bz*sO)[(long)row*N + col] = sigf(v);
        }
      }
    }
  }
}

// ---------------------------------------------------------------- banded attention
// One block per (c,h,b); thread qi owns query row s=c*W+qi. Online softmax over
// [64 global keys] + [768 band keys, tiled by 64], K/V staged f32 in LDS.
__global__ __launch_bounds__(256, 2)
void attn_band(const u16* __restrict__ qkv, const float* __restrict__ mask, u16* __restrict__ ctx)
{
  const int c = blockIdx.x, h = blockIdx.y, b = blockIdx.z;
  const int qi = threadIdx.x;
  const int sq = c*WIN + qi;
  __shared__ float lsK[64*64];
  __shared__ float lsV[64*64];

  float qf[64];
  {
    const u16* qrow = qkv + ((long)(b*SL + sq))*QN + h*HD;
    #pragma unroll
    for (int d8 = 0; d8 < 8; d8++){
      us8 v = *(const us8*)(qrow + d8*8);
      #pragma unroll
      for (int j = 0; j < 8; j++) qf[d8*8+j] = b2f((u16)v[j]) * FOLD;
    }
  }
  float m = -3.0e38f, l = 0.f;
  float o[64];
  #pragma unroll
  for (int d = 0; d < 64; d++) o[d] = 0.f;

  const u16* kbase = qkv + (long)b*SL*QN + DM + h*HD;
  const u16* vbase = kbase + DM;
  const float* mrow = mask + b*SL;

  for (int tile = -1; tile < 12; ++tile){
    const int kp0 = (tile < 0) ? 0 : (c*WIN - WIN + tile*64);
    if (tile >= 0 && (kp0 + 63 < GLB || kp0 >= SL)) continue;   // block-uniform skip
    __syncthreads();   // previous tile's readers done before restage
    #pragma unroll
    for (int i = 0; i < 2; i++){
      int e = ((int)threadIdx.x + i*256) * 8;
      int row = e >> 6, colk = e & 63;
      int kpos = kp0 + row;
      us8 kv = {0,0,0,0,0,0,0,0};
      us8 vv = {0,0,0,0,0,0,0,0};
      if (kpos >= 0 && kpos < SL){
        kv = *(const us8*)(kbase + (long)kpos*QN + colk);
        vv = *(const us8*)(vbase + (long)kpos*QN + colk);
      }
      #pragma unroll
      for (int j = 0; j < 8; j++){
        lsK[e + j] = b2f((u16)kv[j]);
        lsV[e + j] = b2f((u16)vv[j]);
      }
    }
    __syncthreads();

    #pragma unroll 1
    for (int g0 = 0; g0 < 64; g0 += 8){
      float s[8];
      #pragma unroll
      for (int kk = 0; kk < 8; kk++){
        const int kt = g0 + kk;
        const float4* kr = (const float4*)&lsK[kt << 6];
        float a0=0.f, a1=0.f, a2=0.f, a3=0.f;
        #pragma unroll
        for (int d4 = 0; d4 < 16; d4++){
          float4 kv = kr[d4];
          a0 += qf[d4*4+0]*kv.x;
          a1 += qf[d4*4+1]*kv.y;
          a2 += qf[d4*4+2]*kv.z;
          a3 += qf[d4*4+3]*kv.w;
        }
        float sv = (a0+a1)+(a2+a3);
        bool valid;
        if (tile < 0){
          valid = (mrow[kt] > 0.f);
        } else {
          const int kpos = kp0 + kt;
          const int dd = tile*64 + kt - WIN - qi;     // j - W - qi
          int kpc = kpos < 0 ? 0 : (kpos >= SL ? SL-1 : kpos);
          valid = (dd >= -WIN) && (dd <= WIN) && (kpos >= GLB) && (kpos < SL) && (mrow[kpc] > 0.f);
        }
        s[kk] = valid ? sv : NEGS;
      }
      float gm = fmaxf(fmaxf(fmaxf(s[0],s[1]),fmaxf(s[2],s[3])),
                       fmaxf(fmaxf(s[4],s[5]),fmaxf(s[6],s[7])));
      if (__any(gm > m)){
        float mnew = fmaxf(m, gm);
        float sf = exp2f(m - mnew);
        m = mnew;
        l *= sf;
        #pragma unroll
        for (int d = 0; d < 64; d++) o[d] *= sf;
      }
      float psum = 0.f;
      #pragma unroll
      for (int kk = 0; kk < 8; kk++){ s[kk] = exp2f(s[kk] - m); psum += s[kk]; }
      l += psum;
      #pragma unroll
      for (int kk = 0; kk < 8; kk++){
        const float4* vr = (const float4*)&lsV[(g0 + kk) << 6];
        const float pk = s[kk];
        #pragma unroll
        for (int d4 = 0; d4 < 16; d4++){
          float4 vv = vr[d4];
          o[d4*4+0] += pk*vv.x;
          o[d4*4+1] += pk*vv.y;
          o[d4*4+2] += pk*vv.z;
          o[d4*4+3] += pk*vv.w;
        }
      }
    }
  }
  const float rl = 1.f / l;
  u16* crow = ctx + ((long)(b*SL + sq))*DM + h*HD;
  #pragma unroll
  for (int d = 0; d < 64; d += 2){
    u32 pk = (u32)f2b(o[d]*rl) | ((u32)f2b(o[d+1]*rl) << 16);
    *(u32*)(crow + d) = pk;
  }
}

// ---------------------------------------------------------------- global rows (s<G), full attention over S
__global__ __launch_bounds__(256, 2)
void attn_global(const u16* __restrict__ qkv, const float* __restrict__ mask, u16* __restrict__ ctx)
{
  const int g = blockIdx.x, h = blockIdx.y, b = blockIdx.z;
  const int t = threadIdx.x, lane = t & 63, w = t >> 6;
  __shared__ float ps[SL];
  __shared__ float qsh[64];
  __shared__ float red[8];

  const u16* qrow = qkv + ((long)(b*SL + g))*QN + h*HD;
  if (t < 64) qsh[t] = b2f(qrow[t]) * FOLD;
  __syncthreads();
  float qf[64];
  #pragma unroll
  for (int d = 0; d < 64; d++) qf[d] = qsh[d];

  const u16* kb = qkv + (long)b*SL*QN + DM + h*HD;
  const float* mrow = mask + b*SL;
  float sk[16];
  float tmax = -3.0e38f;
  #pragma unroll
  for (int i = 0; i < 16; i++){
    int skey = t*16 + i;
    const u16* krow = kb + (long)skey*QN;
    float a = 0.f;
    #pragma unroll
    for (int d8 = 0; d8 < 8; d8++){
      us8 kv = *(const us8*)(krow + d8*8);
      #pragma unroll
      for (int j = 0; j < 8; j++) a += qf[d8*8+j]*b2f((u16)kv[j]);
    }
    sk[i] = (mrow[skey] > 0.f) ? a : NEGS;
    tmax = fmaxf(tmax, sk[i]);
  }
  tmax = wredmax(tmax);
  if (lane == 0) red[w] = tmax;
  __syncthreads();
  const float m = fmaxf(fmaxf(red[0], red[1]), fmaxf(red[2], red[3]));
  float tsum = 0.f;
  #pragma unroll
  for (int i = 0; i < 16; i++){
    float p = exp2f(sk[i] - m);
    ps[t*16 + i] = p;
    tsum += p;
  }
  tsum = wredsum(tsum);
  if (lane == 0) red[4 + w] = tsum;
  __syncthreads();
  const float linv = 1.f / (red[4] + red[5] + red[6] + red[7]);

  const u16* vb = qkv + (long)b*SL*QN + 2*DM + h*HD + lane;
  float acc = 0.f;
  for (int skey = w*1024; skey < w*1024 + 1024; ++skey)
    acc += ps[skey] * b2f(vb[(long)skey*QN]);
  __syncthreads();
  ps[t] = acc;
  __syncthreads();
  if (t < 64){
    float tot = ps[t] + ps[t+64] + ps[t+128] + ps[t+192];
    ctx[((long)(b*SL + g))*DM + h*HD + t] = f2b(tot * linv);
  }
}

// ---------------------------------------------------------------- LayerNorm + ans/span heads (fused)
__global__ __launch_bounds__(256, 2)
void ln_heads(const float* __restrict__ hbuf, const float* __restrict__ gamma, const float* __restrict__ beta,
              const float* __restrict__ Wa, const float* __restrict__ ba,
              const float* __restrict__ Wsp, const float* __restrict__ bsp,
              float* __restrict__ hn, float* __restrict__ ans, float* __restrict__ span)
{
  const int r = blockIdx.x;
  const int t = threadIdx.x, lane = t & 63, w = t >> 6;
  __shared__ float red[8];
  __shared__ float dred[4][5];
  const float* hrow = hbuf + (long)r*DM;
  float v0 = hrow[t], v1 = hrow[t+256], v2 = hrow[t+512];
  float sum = wredsum(v0 + v1 + v2);
  float sq  = wredsum(v0*v0 + v1*v1 + v2*v2);
  if (lane == 0){ red[w] = sum; red[4+w] = sq; }
  __syncthreads();
  const float mu  = (red[0]+red[1]+red[2]+red[3]) * (1.f/768.f);
  const float msq = (red[4]+red[5]+red[6]+red[7]) * (1.f/768.f);
  const float rstd = rsqrtf(msq - mu*mu + 1e-5f);
  float pa0=0,pa1=0,pa2=0,ps0=0,ps1=0;
  const long base = (long)r*DM;
  #pragma unroll
  for (int jj = 0; jj < 3; jj++){
    const int i = t + jj*256;
    const float hv = (jj==0) ? v0 : (jj==1) ? v1 : v2;
    const float y = (hv - mu)*rstd*gamma[i] + beta[i];
    hn[base + i] = y;
    pa0 += y*Wa[i*3+0]; pa1 += y*Wa[i*3+1]; pa2 += y*Wa[i*3+2];
    ps0 += y*Wsp[i*2+0]; ps1 += y*Wsp[i*2+1];
  }
  pa0 = wredsum(pa0); pa1 = wredsum(pa1); pa2 = wredsum(pa2);
  ps0 = wredsum(ps0); ps1 = wredsum(ps1);
  if (lane == 0){ dred[w][0]=pa0; dred[w][1]=pa1; dred[w][2]=pa2; dred[w][3]=ps0; dred[w][4]=ps1; }
  __syncthreads();
  if (t == 0){
    float A0 = dred[0][0]+dred[1][0]+dred[2][0]+dred[3][0];
    float A1 = dred[0][1]+dred[1][1]+dred[2][1]+dred[3][1];
    float A2 = dred[0][2]+dred[1][2]+dred[2][2]+dred[3][2];
    float S0 = dred[0][3]+dred[1][3]+dred[2][3]+dred[3][3];
    float S1 = dred[0][4]+dred[1][4]+dred[2][4]+dred[3][4];
    ans[(long)r*3+0]  = sigf(A0 + ba[0]);
    ans[(long)r*3+1]  = sigf(A1 + ba[1]);
    ans[(long)r*3+2]  = sigf(A2 + ba[2]);
    span[(long)r*2+0] = sigf(S0 + bsp[0]);
    span[(long)r*2+1] = sigf(S1 + bsp[1]);
  }
}

// ---------------------------------------------------------------- launch
extern "C" void kernel_launch(void* const* d_in, const int* in_sizes, int n_in,
                              void* d_out, int out_size, void* d_ws, size_t ws_size,
                              hipStream_t stream)
{
  const int*   input_ids = (const int*)  d_in[0];
  const float* attn_mask = (const float*)d_in[1];
  const int*   html_idx  = (const int*)  d_in[2];
  const float* embed     = (const float*)d_in[3];
  const float* Wq = (const float*)d_in[4];  const float* bq = (const float*)d_in[5];
  const float* Wk = (const float*)d_in[6];  const float* bk = (const float*)d_in[7];
  const float* Wv = (const float*)d_in[8];  const float* bv = (const float*)d_in[9];
  const float* Wo = (const float*)d_in[10]; const float* bo = (const float*)d_in[11];
  const float* gamma = (const float*)d_in[12]; const float* beta = (const float*)d_in[13];
  const float* Wp = (const float*)d_in[14]; const float* bp = (const float*)d_in[15];
  const float* Wa = (const float*)d_in[16]; const float* ba = (const float*)d_in[17];
  const float* Wsp = (const float*)d_in[18]; const float* bsp = (const float*)d_in[19];

  char* ws = (char*)d_ws;
  size_t off = 0;
  auto take = [&](size_t bytes)->char*{
    char* p = ws + off; off += (bytes + 255) & ~(size_t)255; return p;
  };
  float* x_f    = (float*)take((size_t)8192*768*4);
  u16*   x_b    = (u16*)  take((size_t)8192*768*2);
  u16*   wt_qkv = (u16*)  take((size_t)2304*768*2);
  u16*   wt_o   = (u16*)  take((size_t)768*768*2);
  u16*   wt_p   = (u16*)  take((size_t)768*768*2);
  float* b_qkv  = (float*)take(2304*4);
  u16*   qkv_b  = (u16*)  take((size_t)8192*2304*2);
  u16*   ctx_b  = (u16*)  take((size_t)8192*768*2);
  float* h_f    = (float*)take((size_t)8192*768*4);
  u16*   hr_b   = (u16*)  take((size_t)512*768*2);
  u16*   t_b    = (u16*)  take((size_t)512*768*2);

  float* out_hn   = (float*)d_out;
  float* out_ans  = out_hn  + (size_t)8192*768;
  float* out_span = out_ans + (size_t)8192*3;
  float* out_cond = out_span + (size_t)8192*2;

  // weight / bias packs (cheap, recomputed each call — deterministic)
  transpose_pack<<<2304, 256, 0, stream>>>(Wq, wt_qkv,             768);
  transpose_pack<<<2304, 256, 0, stream>>>(Wk, wt_qkv +   768*768, 768);
  transpose_pack<<<2304, 256, 0, stream>>>(Wv, wt_qkv + 2*768*768, 768);
  transpose_pack<<<2304, 256, 0, stream>>>(Wo, wt_o, 768);
  transpose_pack<<<2304, 256, 0, stream>>>(Wp, wt_p, 768);
  pack_bias<<<9, 256, 0, stream>>>(bq, bk, bv, b_qkv);
  embed_gather<<<6144, 256, 0, stream>>>(input_ids, embed, x_f, x_b);

  // QKV: (8192x768) @ (768x2304)
  gemm_bt<0><<<dim3(18,64,1), 256, 0, stream>>>(x_b, wt_qkv, b_qkv, nullptr,
                                                nullptr, qkv_b, 8192, 2304, 768, 0,0,0);
  // attention
  attn_band  <<<dim3(16,12,2), 256, 0, stream>>>(qkv_b, attn_mask, ctx_b);
  attn_global<<<dim3(64,12,2), 256, 0, stream>>>(qkv_b, attn_mask, ctx_b);
  // h = x + ctx@Wo + bo
  gemm_bt<1><<<dim3(6,64,1), 256, 0, stream>>>(ctx_b, wt_o, bo, x_f,
                                               h_f, nullptr, 8192, 768, 768, 0,0,0);
  // LN + ans/span heads
  ln_heads<<<8192, 256, 0, stream>>>(h_f, gamma, beta, Wa, ba, Wsp, bsp,
                                     out_hn, out_ans, out_span);
  // hr gather, t = relu(hr@Wp+bp), cond = sigmoid(t @ hr^T) per batch
  gather_hr<<<1536, 256, 0, stream>>>(html_idx, out_hn, hr_b);
  gemm_bt<2><<<dim3(6,4,1), 256, 0, stream>>>(hr_b, wt_p, bp, nullptr,
                                              nullptr, t_b, 512, 768, 768, 0,0,0);
  gemm_bt<3><<<dim3(2,2,2), 256, 0, stream>>>(t_b, hr_b, nullptr, nullptr,
                                              out_cond, nullptr, 256, 256, 768,
                                              (long)256*768, (long)256*768, (long)256*256);
}

// Round 2
// 547.202 us; speedup vs baseline: 2.1030x; 2.1030x over previous
//
#include <hip/hip_runtime.h>

typedef unsigned short u16;
typedef unsigned int   u32;
typedef __attribute__((ext_vector_type(8))) short s8v;           // MFMA bf16 frag (8 bf16)
typedef __attribute__((ext_vector_type(8))) unsigned short us8;  // raw bf16x8 load
typedef __attribute__((ext_vector_type(4))) float f4v;           // MFMA acc frag

constexpr int BC  = 2;
constexpr int SL  = 4096;
constexpr int NH  = 12;
constexpr int HD  = 64;
constexpr int DM  = 768;
constexpr int WIN = 256;
constexpr int GLB = 64;
constexpr int QN  = 2304;   // q|k|v packed columns
constexpr float FOLD = 0.125f * 1.44269504088896f; // scale(1/sqrt(64)) * log2(e)
constexpr float NEGS = -1.0e9f;

__device__ __forceinline__ float b2f(u16 b){ return __uint_as_float(((u32)b) << 16); }
__device__ __forceinline__ u16 f2b(float f){
  u32 u = __float_as_uint(f);
  return (u16)((u + 0x7fffu + ((u >> 16) & 1u)) >> 16);  // RNE
}
__device__ __forceinline__ float wredsum(float v){
  #pragma unroll
  for (int o = 32; o > 0; o >>= 1) v += __shfl_xor(v, o, 64);
  return v;
}
__device__ __forceinline__ float wredmax(float v){
  #pragma unroll
  for (int o = 32; o > 0; o >>= 1) v = fmaxf(v, __shfl_xor(v, o, 64));
  return v;
}
__device__ __forceinline__ float sigf(float x){ return 1.f / (1.f + __expf(-x)); }

// ---------------------------------------------------------------- small packs
__global__ void transpose_pack(const float* __restrict__ src, u16* __restrict__ dst, int N){
  int e = blockIdx.x*256 + threadIdx.x;          // e = n*768 + k, dst is Bt[n][k]
  if (e >= N*768) return;
  int n = e / 768, k = e - n*768;
  dst[e] = f2b(src[(long)k*N + n]);
}

__global__ void pack_bias(const float* __restrict__ bq, const float* __restrict__ bk,
                          const float* __restrict__ bv, float* __restrict__ dst){
  int i = blockIdx.x*256 + threadIdx.x;
  if (i >= 2304) return;
  dst[i] = (i < 768) ? bq[i] : (i < 1536) ? bk[i-768] : bv[i-1536];
}

__global__ void embed_gather(const int* __restrict__ ids, const float* __restrict__ emb,
                             float* __restrict__ x, u16* __restrict__ xb){
  int e4 = blockIdx.x*256 + threadIdx.x;         // 8192 rows * 192 float4
  if (e4 >= 8192*192) return;
  int row = e4 / 192, d4 = e4 - row*192;
  int id = ids[row];
  float4 v = ((const float4*)(emb + (long)id*768))[d4];
  ((float4*)(x + (long)row*768))[d4] = v;
  u32 p0 = (u32)f2b(v.x) | ((u32)f2b(v.y) << 16);
  u32 p1 = (u32)f2b(v.z) | ((u32)f2b(v.w) << 16);
  ((u32*)(xb + (long)row*768))[d4*2]   = p0;
  ((u32*)(xb + (long)row*768))[d4*2+1] = p1;
}

__global__ void gather_hr(const int* __restrict__ hidx, const float* __restrict__ hn,
                          u16* __restrict__ hrb){
  int e = blockIdx.x*256 + threadIdx.x;          // 512 rows * 768
  if (e >= 512*768) return;
  int r = e / 768, d = e - r*768;
  int b = r >> 8;
  int idx = hidx[r];
  hrb[e] = f2b(hn[((long)(b*SL + idx))*768 + d]);
}

// ---------------------------------------------------------------- bf16 MFMA GEMM
template<int MODE>
__global__ __launch_bounds__(256, 2)
void gemm_bt(const u16* __restrict__ A, const u16* __restrict__ Bt,
             const float* __restrict__ bias, const float* __restrict__ res,
             float* __restrict__ outF, u16* __restrict__ outB,
             int M, int N, int K, long sA, long sB, long sO)
{
  const int bz = blockIdx.z;
  A  += (long)bz * sA;
  Bt += (long)bz * sB;
  const int n0 = blockIdx.x * 128;
  const int m0 = blockIdx.y * 128;
  __shared__ u16 lsA[128*64];
  __shared__ u16 lsB[128*64];
  const int t = threadIdx.x;
  const int w = t >> 6, lane = t & 63;
  const int wr = w >> 1, wc = w & 1;
  const int fr = lane & 15, fq = lane >> 4;

  f4v acc[4][4];
  #pragma unroll
  for (int i=0;i<4;i++)
    #pragma unroll
    for (int j=0;j<4;j++) acc[i][j] = (f4v)0.f;

  for (int k0 = 0; k0 < K; k0 += 64){
    #pragma unroll
    for (int i=0;i<4;i++){
      int e = (w*4+i)*512 + lane*8;
      int row = e >> 6, col = e & 63;
      __builtin_amdgcn_global_load_lds(
        (const __attribute__((address_space(1))) void*)(A + (long)(m0+row)*K + (k0+col)),
        (__attribute__((address_space(3))) void*)(&lsA[(w*4+i)*512]), 16, 0, 0);
      __builtin_amdgcn_global_load_lds(
        (const __attribute__((address_space(1))) void*)(Bt + (long)(n0+row)*K + (k0+col)),
        (__attribute__((address_space(3))) void*)(&lsB[(w*4+i)*512]), 16, 0, 0);
    }
    __syncthreads();
    #pragma unroll
    for (int kk = 0; kk < 2; kk++){
      s8v af[4], bfv[4];
      #pragma unroll
      for (int mi=0;mi<4;mi++)
        af[mi] = *(const s8v*)&lsA[(wr*64 + mi*16 + fr)*64 + kk*32 + fq*8];
      #pragma unroll
      for (int ni=0;ni<4;ni++)
        bfv[ni] = *(const s8v*)&lsB[(wc*64 + ni*16 + fr)*64 + kk*32 + fq*8];
      #pragma unroll
      for (int mi=0;mi<4;mi++)
        #pragma unroll
        for (int ni=0;ni<4;ni++)
          acc[mi][ni] = __builtin_amdgcn_mfma_f32_16x16x32_bf16(af[mi], bfv[ni], acc[mi][ni], 0, 0, 0);
    }
    __syncthreads();
  }
  #pragma unroll
  for (int mi=0;mi<4;mi++){
    #pragma unroll
    for (int ni=0;ni<4;ni++){
      #pragma unroll
      for (int r=0;r<4;r++){
        int row = m0 + wr*64 + mi*16 + fq*4 + r;
        int col = n0 + wc*64 + ni*16 + fr;
        float v = acc[mi][ni][r];
        if constexpr (MODE == 0){
          v += bias[col];
          outB[(long)row*N + col] = f2b(v);
        } else if constexpr (MODE == 1){
          v += bias[col] + res[(long)row*N + col];
          outF[(long)row*N + col] = v;
        } else if constexpr (MODE == 2){
          v = fmaxf(v + bias[col], 0.f);
          outB[(long)row*N + col] = f2b(v);
        } else {
          (outF + bz*sO)[(long)row*N + col] = sigf(v);
        }
      }
    }
  }
}

// ---------------------------------------------------------------- banded attention, MFMA flash
// Grid (S/64, H, B); 4 waves x 16 query rows. Per key-tile (64 keys):
//   K staged via global_load_lds with pre-swizzled source (conflict-free b128 frag reads)
//   V staged reg->LDS transposed [64d][72] (lane=k so scalar writes are 2-way)
//   S = QK^T via mfma 16x16x32; online softmax per wave; P round-trip through LDS; PV via mfma.
__global__ __launch_bounds__(256, 2)
void attn_band_mfma(const u16* __restrict__ qkv, const float* __restrict__ mask, u16* __restrict__ ctx)
{
  const int q0 = blockIdx.x * 64;
  const int h = blockIdx.y, b = blockIdx.z;
  const int t = threadIdx.x;
  const int w = t >> 6, lane = t & 63;
  const int fq = lane >> 4, fr = lane & 15;

  __shared__ u16 lsK[64*64];       // row r: 16B chunk c8 holds K[r][(c8^(r&7))*8 ..+8)
  __shared__ u16 lsVT[64*72];      // V^T[d][k], row stride 72 elems (144B)
  __shared__ u16 lsP[4][16*72];    // per-wave P, row stride 72
  __shared__ float lsM[64];

  const long bq = (long)b*SL*QN;
  const u16* qrow = qkv + (bq + (long)(q0 + w*16 + fr)*QN) + h*HD;
  s8v aq[2];
  aq[0] = *(const s8v*)(qrow + fq*8);
  aq[1] = *(const s8v*)(qrow + 32 + fq*8);

  const u16* kq = qkv + bq + DM + h*HD;
  const u16* vq = qkv + bq + 2*DM + h*HD;
  const float* mrow = mask + b*SL;

  f4v out[4];
  #pragma unroll
  for (int n=0;n<4;n++) out[n] = (f4v)0.f;
  float m[4]  = {-3.0e38f,-3.0e38f,-3.0e38f,-3.0e38f};
  float l[4]  = {0.f,0.f,0.f,0.f};

  for (int ti = -1; ti < 9; ++ti){
    const int k0 = (ti < 0) ? 0 : (q0 - 256 + ti*64);
    if (ti >= 0 && (k0 < GLB || k0 >= SL)) continue;   // block-uniform
    __syncthreads();                                   // readers of prev tile done
    if (t < 64) lsM[t] = mrow[k0 + t];
    #pragma unroll
    for (int j=0;j<2;j++){                             // K: 8 rows per instr per wave
      const int r = (w*2+j)*8 + (lane>>3);
      const int d = ((lane&7) ^ (lane>>3))*8;          // pre-swizzled source col
      __builtin_amdgcn_global_load_lds(
        (const __attribute__((address_space(1))) void*)(kq + (long)(k0+r)*QN + d),
        (__attribute__((address_space(3))) void*)(&lsK[(w*2+j)*512]), 16, 0, 0);
    }
    #pragma unroll
    for (int j=0;j<2;j++){                             // V^T: lane = k row
      const int d0 = w*8 + j*32;
      us8 vv = *(const us8*)(vq + (long)(k0+lane)*QN + d0);
      #pragma unroll
      for (int jj=0;jj<8;jj++) lsVT[(d0+jj)*72 + lane] = (u16)vv[jj];
    }
    __syncthreads();

    // S = Q K^T   (S[q=fq*4+r][k=16n+fr])
    f4v s[4];
    #pragma unroll
    for (int n=0;n<4;n++) s[n] = (f4v)0.f;
    #pragma unroll
    for (int kk=0;kk<2;kk++){
      #pragma unroll
      for (int n=0;n<4;n++){
        s8v bf = *(const s8v*)&lsK[(16*n+fr)*64 + (((kk*4+fq) ^ (fr&7))<<3)];
        s[n] = __builtin_amdgcn_mfma_f32_16x16x32_bf16(aq[kk], bf, s[n], 0,0,0);
      }
    }
    // mask + scale
    const bool isg = (ti < 0);
    #pragma unroll
    for (int n=0;n<4;n++){
      const int kcol = 16*n + fr;
      const float mk = lsM[kcol];
      #pragma unroll
      for (int r=0;r<4;r++){
        const int dd = k0 + kcol - (q0 + w*16 + fq*4 + r);
        const bool valid = (mk > 0.f) && (isg || (dd >= -WIN && dd <= WIN));
        s[n][r] = valid ? s[n][r]*FOLD : NEGS;
      }
    }
    // online softmax (reduce over fr lanes)
    float sf[4];
    #pragma unroll
    for (int r=0;r<4;r++){
      float rm = fmaxf(fmaxf(s[0][r], s[1][r]), fmaxf(s[2][r], s[3][r]));
      rm = fmaxf(rm, __shfl_xor(rm, 1, 64));
      rm = fmaxf(rm, __shfl_xor(rm, 2, 64));
      rm = fmaxf(rm, __shfl_xor(rm, 4, 64));
      rm = fmaxf(rm, __shfl_xor(rm, 8, 64));
      const float mn = fmaxf(m[r], rm);
      sf[r] = exp2f(m[r] - mn);
      m[r] = mn;
    }
    u16* lsPw = lsP[w];
    float rs[4] = {0.f,0.f,0.f,0.f};
    #pragma unroll
    for (int n=0;n<4;n++){
      #pragma unroll
      for (int r=0;r<4;r++){
        float p = exp2f(s[n][r] - m[r]);
        rs[r] += p;
        lsPw[(fq*4+r)*72 + 16*n + fr] = f2b(p);
        out[n][r] *= sf[r];
      }
    }
    #pragma unroll
    for (int r=0;r<4;r++){
      float rv = rs[r];
      rv += __shfl_xor(rv, 1, 64);
      rv += __shfl_xor(rv, 2, 64);
      rv += __shfl_xor(rv, 4, 64);
      rv += __shfl_xor(rv, 8, 64);
      l[r] = l[r]*sf[r] + rv;
    }
    // PV
    s8v ap[2];
    ap[0] = *(const s8v*)&lsPw[fr*72 + fq*8];
    ap[1] = *(const s8v*)&lsPw[fr*72 + 32 + fq*8];
    #pragma unroll
    for (int kk=0;kk<2;kk++){
      #pragma unroll
      for (int n=0;n<4;n++){
        s8v bv = *(const s8v*)&lsVT[(16*n+fr)*72 + kk*32 + fq*8];
        out[n] = __builtin_amdgcn_mfma_f32_16x16x32_bf16(ap[kk], bv, out[n], 0,0,0);
      }
    }
  }
  #pragma unroll
  for (int r=0;r<4;r++) l[r] = 1.f/l[r];
  u16* cb = ctx + (((long)(b*SL) + q0 + w*16 + fq*4))*DM + h*HD + fr;
  #pragma unroll
  for (int n=0;n<4;n++)
    #pragma unroll
    for (int r=0;r<4;r++)
      cb[(long)r*DM + 16*n] = f2b(out[n][r]*l[r]);
}

// ---------------------------------------------------------------- global rows (s<G), full attention over S
__global__ __launch_bounds__(256, 2)
void attn_global(const u16* __restrict__ qkv, const float* __restrict__ mask, u16* __restrict__ ctx)
{
  const int g = blockIdx.x, h = blockIdx.y, b = blockIdx.z;
  const int t = threadIdx.x, lane = t & 63, w = t >> 6;
  __shared__ float ps[SL];
  __shared__ float qsh[64];
  __shared__ float red[8];

  const u16* qrow = qkv + ((long)(b*SL + g))*QN + h*HD;
  if (t < 64) qsh[t] = b2f(qrow[t]) * FOLD;
  __syncthreads();
  float qf[64];
  #pragma unroll
  for (int d = 0; d < 64; d++) qf[d] = qsh[d];

  const u16* kb = qkv + (long)b*SL*QN + DM + h*HD;
  const float* mrow = mask + b*SL;
  float sk[16];
  float tmax = -3.0e38f;
  #pragma unroll
  for (int i = 0; i < 16; i++){
    int skey = t*16 + i;
    const u16* krow = kb + (long)skey*QN;
    float a = 0.f;
    #pragma unroll
    for (int d8 = 0; d8 < 8; d8++){
      us8 kv = *(const us8*)(krow + d8*8);
      #pragma unroll
      for (int j = 0; j < 8; j++) a += qf[d8*8+j]*b2f((u16)kv[j]);
    }
    sk[i] = (mrow[skey] > 0.f) ? a : NEGS;
    tmax = fmaxf(tmax, sk[i]);
  }
  tmax = wredmax(tmax);
  if (lane == 0) red[w] = tmax;
  __syncthreads();
  const float m = fmaxf(fmaxf(red[0], red[1]), fmaxf(red[2], red[3]));
  float tsum = 0.f;
  #pragma unroll
  for (int i = 0; i < 16; i++){
    float p = exp2f(sk[i] - m);
    ps[t*16 + i] = p;
    tsum += p;
  }
  tsum = wredsum(tsum);
  if (lane == 0) red[4 + w] = tsum;
  __syncthreads();
  const float linv = 1.f / (red[4] + red[5] + red[6] + red[7]);

  const u16* vb = qkv + (long)b*SL*QN + 2*DM + h*HD + lane;
  float acc = 0.f;
  for (int skey = w*1024; skey < w*1024 + 1024; ++skey)
    acc += ps[skey] * b2f(vb[(long)skey*QN]);
  __syncthreads();
  ps[t] = acc;
  __syncthreads();
  if (t < 64){
    float tot = ps[t] + ps[t+64] + ps[t+128] + ps[t+192];
    ctx[((long)(b*SL + g))*DM + h*HD + t] = f2b(tot * linv);
  }
}

// ---------------------------------------------------------------- LayerNorm + ans/span heads (fused)
__global__ __launch_bounds__(256, 2)
void ln_heads(const float* __restrict__ hbuf, const float* __restrict__ gamma, const float* __restrict__ beta,
              const float* __restrict__ Wa, const float* __restrict__ ba,
              const float* __restrict__ Wsp, const float* __restrict__ bsp,
              float* __restrict__ hn, float* __restrict__ ans, float* __restrict__ span)
{
  const int r = blockIdx.x;
  const int t = threadIdx.x, lane = t & 63, w = t >> 6;
  __shared__ float red[8];
  __shared__ float dred[4][5];
  const float* hrow = hbuf + (long)r*DM;
  float v0 = hrow[t], v1 = hrow[t+256], v2 = hrow[t+512];
  float sum = wredsum(v0 + v1 + v2);
  float sq  = wredsum(v0*v0 + v1*v1 + v2*v2);
  if (lane == 0){ red[w] = sum; red[4+w] = sq; }
  __syncthreads();
  const float mu  = (red[0]+red[1]+red[2]+red[3]) * (1.f/768.f);
  const float msq = (red[4]+red[5]+red[6]+red[7]) * (1.f/768.f);
  const float rstd = rsqrtf(msq - mu*mu + 1e-5f);
  float pa0=0,pa1=0,pa2=0,ps0=0,ps1=0;
  const long base = (long)r*DM;
  #pragma unroll
  for (int jj = 0; jj < 3; jj++){
    const int i = t + jj*256;
    const float hv = (jj==0) ? v0 : (jj==1) ? v1 : v2;
    const float y = (hv - mu)*rstd*gamma[i] + beta[i];
    hn[base + i] = y;
    pa0 += y*Wa[i*3+0]; pa1 += y*Wa[i*3+1]; pa2 += y*Wa[i*3+2];
    ps0 += y*Wsp[i*2+0]; ps1 += y*Wsp[i*2+1];
  }
  pa0 = wredsum(pa0); pa1 = wredsum(pa1); pa2 = wredsum(pa2);
  ps0 = wredsum(ps0); ps1 = wredsum(ps1);
  if (lane == 0){ dred[w][0]=pa0; dred[w][1]=pa1; dred[w][2]=pa2; dred[w][3]=ps0; dred[w][4]=ps1; }
  __syncthreads();
  if (t == 0){
    float A0 = dred[0][0]+dred[1][0]+dred[2][0]+dred[3][0];
    float A1 = dred[0][1]+dred[1][1]+dred[2][1]+dred[3][1];
    float A2 = dred[0][2]+dred[1][2]+dred[2][2]+dred[3][2];
    float S0 = dred[0][3]+dred[1][3]+dred[2][3]+dred[3][3];
    float S1 = dred[0][4]+dred[1][4]+dred[2][4]+dred[3][4];
    ans[(long)r*3+0]  = sigf(A0 + ba[0]);
    ans[(long)r*3+1]  = sigf(A1 + ba[1]);
    ans[(long)r*3+2]  = sigf(A2 + ba[2]);
    span[(long)r*2+0] = sigf(S0 + bsp[0]);
    span[(long)r*2+1] = sigf(S1 + bsp[1]);
  }
}

// ---------------------------------------------------------------- launch
extern "C" void kernel_launch(void* const* d_in, const int* in_sizes, int n_in,
                              void* d_out, int out_size, void* d_ws, size_t ws_size,
                              hipStream_t stream)
{
  const int*   input_ids = (const int*)  d_in[0];
  const float* attn_mask = (const float*)d_in[1];
  const int*   html_idx  = (const int*)  d_in[2];
  const float* embed     = (const float*)d_in[3];
  const float* Wq = (const float*)d_in[4];  const float* bq = (const float*)d_in[5];
  const float* Wk = (const float*)d_in[6];  const float* bk = (const float*)d_in[7];
  const float* Wv = (const float*)d_in[8];  const float* bv = (const float*)d_in[9];
  const float* Wo = (const float*)d_in[10]; const float* bo = (const float*)d_in[11];
  const float* gamma = (const float*)d_in[12]; const float* beta = (const float*)d_in[13];
  const float* Wp = (const float*)d_in[14]; const float* bp = (const float*)d_in[15];
  const float* Wa = (const float*)d_in[16]; const float* ba = (const float*)d_in[17];
  const float* Wsp = (const float*)d_in[18]; const float* bsp = (const float*)d_in[19];

  char* ws = (char*)d_ws;
  size_t off = 0;
  auto take = [&](size_t bytes)->char*{
    char* p = ws + off; off += (bytes + 255) & ~(size_t)255; return p;
  };
  float* x_f    = (float*)take((size_t)8192*768*4);
  u16*   x_b    = (u16*)  take((size_t)8192*768*2);
  u16*   wt_qkv = (u16*)  take((size_t)2304*768*2);
  u16*   wt_o   = (u16*)  take((size_t)768*768*2);
  u16*   wt_p   = (u16*)  take((size_t)768*768*2);
  float* b_qkv  = (float*)take(2304*4);
  u16*   qkv_b  = (u16*)  take((size_t)8192*2304*2);
  u16*   ctx_b  = (u16*)  take((size_t)8192*768*2);
  float* h_f    = (float*)take((size_t)8192*768*4);
  u16*   hr_b   = (u16*)  take((size_t)512*768*2);
  u16*   t_b    = (u16*)  take((size_t)512*768*2);

  float* out_hn   = (float*)d_out;
  float* out_ans  = out_hn  + (size_t)8192*768;
  float* out_span = out_ans + (size_t)8192*3;
  float* out_cond = out_span + (size_t)8192*2;

  transpose_pack<<<2304, 256, 0, stream>>>(Wq, wt_qkv,             768);
  transpose_pack<<<2304, 256, 0, stream>>>(Wk, wt_qkv +   768*768, 768);
  transpose_pack<<<2304, 256, 0, stream>>>(Wv, wt_qkv + 2*768*768, 768);
  transpose_pack<<<2304, 256, 0, stream>>>(Wo, wt_o, 768);
  transpose_pack<<<2304, 256, 0, stream>>>(Wp, wt_p, 768);
  pack_bias<<<9, 256, 0, stream>>>(bq, bk, bv, b_qkv);
  embed_gather<<<6144, 256, 0, stream>>>(input_ids, embed, x_f, x_b);

  gemm_bt<0><<<dim3(18,64,1), 256, 0, stream>>>(x_b, wt_qkv, b_qkv, nullptr,
                                                nullptr, qkv_b, 8192, 2304, 768, 0,0,0);
  attn_band_mfma<<<dim3(64,12,2), 256, 0, stream>>>(qkv_b, attn_mask, ctx_b);
  attn_global   <<<dim3(64,12,2), 256, 0, stream>>>(qkv_b, attn_mask, ctx_b);
  gemm_bt<1><<<dim3(6,64,1), 256, 0, stream>>>(ctx_b, wt_o, bo, x_f,
                                               h_f, nullptr, 8192, 768, 768, 0,0,0);
  ln_heads<<<8192, 256, 0, stream>>>(h_f, gamma, beta, Wa, ba, Wsp, bsp,
                                     out_hn, out_ans, out_span);
  gather_hr<<<1536, 256, 0, stream>>>(html_idx, out_hn, hr_b);
  gemm_bt<2><<<dim3(6,4,1), 256, 0, stream>>>(hr_b, wt_p, bp, nullptr,
                                              nullptr, t_b, 512, 768, 768, 0,0,0);
  gemm_bt<3><<<dim3(2,2,2), 256, 0, stream>>>(t_b, hr_b, nullptr, nullptr,
                                              out_cond, nullptr, 256, 256, 768,
                                              (long)256*768, (long)256*768, (long)256*256);
}

// Round 3
// 263.287 us; speedup vs baseline: 4.3708x; 2.0783x over previous
//
#include <hip/hip_runtime.h>

typedef unsigned short u16;
typedef unsigned int   u32;
typedef __attribute__((ext_vector_type(8))) short s8v;           // MFMA bf16 frag (8 bf16)
typedef __attribute__((ext_vector_type(8))) unsigned short us8;  // raw bf16x8 load
typedef __attribute__((ext_vector_type(4))) float f4v;           // MFMA acc frag

constexpr int BC  = 2;
constexpr int SL  = 4096;
constexpr int NH  = 12;
constexpr int HD  = 64;
constexpr int DM  = 768;
constexpr int WIN = 256;
constexpr int GLB = 64;
constexpr int QN  = 2304;   // q|k|v packed columns
constexpr int KCH = 16;     // global-attn key chunks
constexpr float FOLD = 0.125f * 1.44269504088896f; // scale(1/sqrt(64)) * log2(e)
constexpr float NEGS = -1.0e9f;

__device__ __forceinline__ float b2f(u16 b){ return __uint_as_float(((u32)b) << 16); }
__device__ __forceinline__ u16 f2b(float f){
  u32 u = __float_as_uint(f);
  return (u16)((u + 0x7fffu + ((u >> 16) & 1u)) >> 16);  // RNE
}
__device__ __forceinline__ float wredsum(float v){
  #pragma unroll
  for (int o = 32; o > 0; o >>= 1) v += __shfl_xor(v, o, 64);
  return v;
}
__device__ __forceinline__ float sigf(float x){ return 1.f / (1.f + __expf(-x)); }

// ---------------------------------------------------------------- small packs
__global__ void transpose_pack(const float* __restrict__ src, u16* __restrict__ dst, int N){
  int e = blockIdx.x*256 + threadIdx.x;          // e = n*768 + k, dst is Bt[n][k]
  if (e >= N*768) return;
  int n = e / 768, k = e - n*768;
  dst[e] = f2b(src[(long)k*N + n]);
}

__global__ void pack_bias(const float* __restrict__ bq, const float* __restrict__ bk,
                          const float* __restrict__ bv, float* __restrict__ dst){
  int i = blockIdx.x*256 + threadIdx.x;
  if (i >= 2304) return;
  dst[i] = (i < 768) ? bq[i] : (i < 1536) ? bk[i-768] : bv[i-1536];
}

__global__ void embed_gather(const int* __restrict__ ids, const float* __restrict__ emb,
                             float* __restrict__ x, u16* __restrict__ xb){
  int e4 = blockIdx.x*256 + threadIdx.x;         // 8192 rows * 192 float4
  if (e4 >= 8192*192) return;
  int row = e4 / 192, d4 = e4 - row*192;
  int id = ids[row];
  float4 v = ((const float4*)(emb + (long)id*768))[d4];
  ((float4*)(x + (long)row*768))[d4] = v;
  u32 p0 = (u32)f2b(v.x) | ((u32)f2b(v.y) << 16);
  u32 p1 = (u32)f2b(v.z) | ((u32)f2b(v.w) << 16);
  ((u32*)(xb + (long)row*768))[d4*2]   = p0;
  ((u32*)(xb + (long)row*768))[d4*2+1] = p1;
}

__global__ void gather_hr(const int* __restrict__ hidx, const float* __restrict__ hn,
                          u16* __restrict__ hrb){
  int e = blockIdx.x*256 + threadIdx.x;          // 512 rows * 768
  if (e >= 512*768) return;
  int r = e / 768, d = e - r*768;
  int b = r >> 8;
  int idx = hidx[r];
  hrb[e] = f2b(hn[((long)(b*SL + idx))*768 + d]);
}

// ---------------------------------------------------------------- bf16 MFMA GEMM
template<int MODE>
__global__ __launch_bounds__(256, 2)
void gemm_bt(const u16* __restrict__ A, const u16* __restrict__ Bt,
             const float* __restrict__ bias, const float* __restrict__ res,
             float* __restrict__ outF, u16* __restrict__ outB,
             int M, int N, int K, long sA, long sB, long sO)
{
  const int bz = blockIdx.z;
  A  += (long)bz * sA;
  Bt += (long)bz * sB;
  const int n0 = blockIdx.x * 128;
  const int m0 = blockIdx.y * 128;
  __shared__ u16 lsA[128*64];
  __shared__ u16 lsB[128*64];
  const int t = threadIdx.x;
  const int w = t >> 6, lane = t & 63;
  const int wr = w >> 1, wc = w & 1;
  const int fr = lane & 15, fq = lane >> 4;

  f4v acc[4][4];
  #pragma unroll
  for (int i=0;i<4;i++)
    #pragma unroll
    for (int j=0;j<4;j++) acc[i][j] = (f4v)0.f;

  for (int k0 = 0; k0 < K; k0 += 64){
    #pragma unroll
    for (int i=0;i<4;i++){
      int e = (w*4+i)*512 + lane*8;
      int row = e >> 6, col = e & 63;
      __builtin_amdgcn_global_load_lds(
        (const __attribute__((address_space(1))) void*)(A + (long)(m0+row)*K + (k0+col)),
        (__attribute__((address_space(3))) void*)(&lsA[(w*4+i)*512]), 16, 0, 0);
      __builtin_amdgcn_global_load_lds(
        (const __attribute__((address_space(1))) void*)(Bt + (long)(n0+row)*K + (k0+col)),
        (__attribute__((address_space(3))) void*)(&lsB[(w*4+i)*512]), 16, 0, 0);
    }
    __syncthreads();
    #pragma unroll
    for (int kk = 0; kk < 2; kk++){
      s8v af[4], bfv[4];
      #pragma unroll
      for (int mi=0;mi<4;mi++)
        af[mi] = *(const s8v*)&lsA[(wr*64 + mi*16 + fr)*64 + kk*32 + fq*8];
      #pragma unroll
      for (int ni=0;ni<4;ni++)
        bfv[ni] = *(const s8v*)&lsB[(wc*64 + ni*16 + fr)*64 + kk*32 + fq*8];
      #pragma unroll
      for (int mi=0;mi<4;mi++)
        #pragma unroll
        for (int ni=0;ni<4;ni++)
          acc[mi][ni] = __builtin_amdgcn_mfma_f32_16x16x32_bf16(af[mi], bfv[ni], acc[mi][ni], 0, 0, 0);
    }
    __syncthreads();
  }
  #pragma unroll
  for (int mi=0;mi<4;mi++){
    #pragma unroll
    for (int ni=0;ni<4;ni++){
      #pragma unroll
      for (int r=0;r<4;r++){
        int row = m0 + wr*64 + mi*16 + fq*4 + r;
        int col = n0 + wc*64 + ni*16 + fr;
        float v = acc[mi][ni][r];
        if constexpr (MODE == 0){
          v += bias[col];
          outB[(long)row*N + col] = f2b(v);
        } else if constexpr (MODE == 1){
          v += bias[col] + res[(long)row*N + col];
          outF[(long)row*N + col] = v;
        } else if constexpr (MODE == 2){
          v = fmaxf(v + bias[col], 0.f);
          outB[(long)row*N + col] = f2b(v);
        } else {
          (outF + bz*sO)[(long)row*N + col] = sigf(v);
        }
      }
    }
  }
}

// ---------------------------------------------------------------- banded attention, MFMA flash
__global__ __launch_bounds__(256, 2)
void attn_band_mfma(const u16* __restrict__ qkv, const float* __restrict__ mask, u16* __restrict__ ctx)
{
  const int q0 = blockIdx.x * 64;
  const int h = blockIdx.y, b = blockIdx.z;
  const int t = threadIdx.x;
  const int w = t >> 6, lane = t & 63;
  const int fq = lane >> 4, fr = lane & 15;

  __shared__ u16 lsK[64*64];       // row r: 16B chunk c8 holds K[r][(c8^(r&7))*8 ..+8)
  __shared__ u16 lsVT[64*72];      // V^T[d][k], row stride 72 elems (144B)
  __shared__ u16 lsP[4][16*72];    // per-wave P, row stride 72
  __shared__ float lsM[64];

  const long bq = (long)b*SL*QN;
  const u16* qrow = qkv + (bq + (long)(q0 + w*16 + fr)*QN) + h*HD;
  s8v aq[2];
  aq[0] = *(const s8v*)(qrow + fq*8);
  aq[1] = *(const s8v*)(qrow + 32 + fq*8);

  const u16* kq = qkv + bq + DM + h*HD;
  const u16* vq = qkv + bq + 2*DM + h*HD;
  const float* mrow = mask + b*SL;

  f4v out[4];
  #pragma unroll
  for (int n=0;n<4;n++) out[n] = (f4v)0.f;
  float m[4]  = {-3.0e38f,-3.0e38f,-3.0e38f,-3.0e38f};
  float l[4]  = {0.f,0.f,0.f,0.f};

  for (int ti = -1; ti < 9; ++ti){
    const int k0 = (ti < 0) ? 0 : (q0 - 256 + ti*64);
    if (ti >= 0 && (k0 < GLB || k0 >= SL)) continue;   // block-uniform
    __syncthreads();                                   // readers of prev tile done
    if (t < 64) lsM[t] = mrow[k0 + t];
    #pragma unroll
    for (int j=0;j<2;j++){                             // K: 8 rows per instr per wave
      const int r = (w*2+j)*8 + (lane>>3);
      const int d = ((lane&7) ^ (lane>>3))*8;          // pre-swizzled source col
      __builtin_amdgcn_global_load_lds(
        (const __attribute__((address_space(1))) void*)(kq + (long)(k0+r)*QN + d),
        (__attribute__((address_space(3))) void*)(&lsK[(w*2+j)*512]), 16, 0, 0);
    }
    #pragma unroll
    for (int j=0;j<2;j++){                             // V^T: lane = k row
      const int d0 = w*8 + j*32;
      us8 vv = *(const us8*)(vq + (long)(k0+lane)*QN + d0);
      #pragma unroll
      for (int jj=0;jj<8;jj++) lsVT[(d0+jj)*72 + lane] = (u16)vv[jj];
    }
    __syncthreads();

    // S = Q K^T   (S[q=fq*4+r][k=16n+fr])
    f4v s[4];
    #pragma unroll
    for (int n=0;n<4;n++) s[n] = (f4v)0.f;
    #pragma unroll
    for (int kk=0;kk<2;kk++){
      #pragma unroll
      for (int n=0;n<4;n++){
        s8v bf = *(const s8v*)&lsK[(16*n+fr)*64 + (((kk*4+fq) ^ (fr&7))<<3)];
        s[n] = __builtin_amdgcn_mfma_f32_16x16x32_bf16(aq[kk], bf, s[n], 0,0,0);
      }
    }
    const bool isg = (ti < 0);
    #pragma unroll
    for (int n=0;n<4;n++){
      const int kcol = 16*n + fr;
      const float mk = lsM[kcol];
      #pragma unroll
      for (int r=0;r<4;r++){
        const int dd = k0 + kcol - (q0 + w*16 + fq*4 + r);
        const bool valid = (mk > 0.f) && (isg || (dd >= -WIN && dd <= WIN));
        s[n][r] = valid ? s[n][r]*FOLD : NEGS;
      }
    }
    float sf[4];
    #pragma unroll
    for (int r=0;r<4;r++){
      float rm = fmaxf(fmaxf(s[0][r], s[1][r]), fmaxf(s[2][r], s[3][r]));
      rm = fmaxf(rm, __shfl_xor(rm, 1, 64));
      rm = fmaxf(rm, __shfl_xor(rm, 2, 64));
      rm = fmaxf(rm, __shfl_xor(rm, 4, 64));
      rm = fmaxf(rm, __shfl_xor(rm, 8, 64));
      const float mn = fmaxf(m[r], rm);
      sf[r] = exp2f(m[r] - mn);
      m[r] = mn;
    }
    u16* lsPw = lsP[w];
    float rs[4] = {0.f,0.f,0.f,0.f};
    #pragma unroll
    for (int n=0;n<4;n++){
      #pragma unroll
      for (int r=0;r<4;r++){
        float p = exp2f(s[n][r] - m[r]);
        rs[r] += p;
        lsPw[(fq*4+r)*72 + 16*n + fr] = f2b(p);
        out[n][r] *= sf[r];
      }
    }
    #pragma unroll
    for (int r=0;r<4;r++){
      float rv = rs[r];
      rv += __shfl_xor(rv, 1, 64);
      rv += __shfl_xor(rv, 2, 64);
      rv += __shfl_xor(rv, 4, 64);
      rv += __shfl_xor(rv, 8, 64);
      l[r] = l[r]*sf[r] + rv;
    }
    s8v ap[2];
    ap[0] = *(const s8v*)&lsPw[fr*72 + fq*8];
    ap[1] = *(const s8v*)&lsPw[fr*72 + 32 + fq*8];
    #pragma unroll
    for (int kk=0;kk<2;kk++){
      #pragma unroll
      for (int n=0;n<4;n++){
        s8v bv = *(const s8v*)&lsVT[(16*n+fr)*72 + kk*32 + fq*8];
        out[n] = __builtin_amdgcn_mfma_f32_16x16x32_bf16(ap[kk], bv, out[n], 0,0,0);
      }
    }
  }
  #pragma unroll
  for (int r=0;r<4;r++) l[r] = 1.f/l[r];
  u16* cb = ctx + (((long)(b*SL) + q0 + w*16 + fq*4))*DM + h*HD + fr;
  #pragma unroll
  for (int n=0;n<4;n++)
    #pragma unroll
    for (int r=0;r<4;r++)
      cb[(long)r*DM + 16*n] = f2b(out[n][r]*l[r]);
}

// ---------------------------------------------------------------- global rows, MFMA flash partials
// Grid (KCH, H, B): each block covers q-rows 0..63 and a 256-key chunk (4 tiles).
// Writes unnormalized f32 out + per-row (m,l) partials; combine kernel merges.
__global__ __launch_bounds__(256, 2)
void attn_global_part(const u16* __restrict__ qkv, const float* __restrict__ mask,
                      float* __restrict__ pout, float* __restrict__ pml)
{
  const int ck = blockIdx.x;
  const int h = blockIdx.y, b = blockIdx.z;
  const int bh = b*NH + h;
  const int t = threadIdx.x;
  const int w = t >> 6, lane = t & 63;
  const int fq = lane >> 4, fr = lane & 15;

  __shared__ u16 lsK[64*64];
  __shared__ u16 lsVT[64*72];
  __shared__ u16 lsP[4][16*72];
  __shared__ float lsM[64];

  const long bq = (long)b*SL*QN;
  const u16* qrow = qkv + (bq + (long)(w*16 + fr)*QN) + h*HD;   // q rows 0..63
  s8v aq[2];
  aq[0] = *(const s8v*)(qrow + fq*8);
  aq[1] = *(const s8v*)(qrow + 32 + fq*8);

  const u16* kq = qkv + bq + DM + h*HD;
  const u16* vq = qkv + bq + 2*DM + h*HD;
  const float* mrow = mask + b*SL;

  f4v out[4];
  #pragma unroll
  for (int n=0;n<4;n++) out[n] = (f4v)0.f;
  float m[4]  = {-3.0e38f,-3.0e38f,-3.0e38f,-3.0e38f};
  float l[4]  = {0.f,0.f,0.f,0.f};

  for (int ti = 0; ti < 4; ++ti){
    const int k0 = ck*256 + ti*64;
    __syncthreads();
    if (t < 64) lsM[t] = mrow[k0 + t];
    #pragma unroll
    for (int j=0;j<2;j++){
      const int r = (w*2+j)*8 + (lane>>3);
      const int d = ((lane&7) ^ (lane>>3))*8;
      __builtin_amdgcn_global_load_lds(
        (const __attribute__((address_space(1))) void*)(kq + (long)(k0+r)*QN + d),
        (__attribute__((address_space(3))) void*)(&lsK[(w*2+j)*512]), 16, 0, 0);
    }
    #pragma unroll
    for (int j=0;j<2;j++){
      const int d0 = w*8 + j*32;
      us8 vv = *(const us8*)(vq + (long)(k0+lane)*QN + d0);
      #pragma unroll
      for (int jj=0;jj<8;jj++) lsVT[(d0+jj)*72 + lane] = (u16)vv[jj];
    }
    __syncthreads();

    f4v s[4];
    #pragma unroll
    for (int n=0;n<4;n++) s[n] = (f4v)0.f;
    #pragma unroll
    for (int kk=0;kk<2;kk++){
      #pragma unroll
      for (int n=0;n<4;n++){
        s8v bf = *(const s8v*)&lsK[(16*n+fr)*64 + (((kk*4+fq) ^ (fr&7))<<3)];
        s[n] = __builtin_amdgcn_mfma_f32_16x16x32_bf16(aq[kk], bf, s[n], 0,0,0);
      }
    }
    #pragma unroll
    for (int n=0;n<4;n++){
      const float mk = lsM[16*n + fr];
      #pragma unroll
      for (int r=0;r<4;r++)
        s[n][r] = (mk > 0.f) ? s[n][r]*FOLD : NEGS;
    }
    float sf[4];
    #pragma unroll
    for (int r=0;r<4;r++){
      float rm = fmaxf(fmaxf(s[0][r], s[1][r]), fmaxf(s[2][r], s[3][r]));
      rm = fmaxf(rm, __shfl_xor(rm, 1, 64));
      rm = fmaxf(rm, __shfl_xor(rm, 2, 64));
      rm = fmaxf(rm, __shfl_xor(rm, 4, 64));
      rm = fmaxf(rm, __shfl_xor(rm, 8, 64));
      const float mn = fmaxf(m[r], rm);
      sf[r] = exp2f(m[r] - mn);
      m[r] = mn;
    }
    u16* lsPw = lsP[w];
    float rs[4] = {0.f,0.f,0.f,0.f};
    #pragma unroll
    for (int n=0;n<4;n++){
      #pragma unroll
      for (int r=0;r<4;r++){
        float p = exp2f(s[n][r] - m[r]);
        rs[r] += p;
        lsPw[(fq*4+r)*72 + 16*n + fr] = f2b(p);
        out[n][r] *= sf[r];
      }
    }
    #pragma unroll
    for (int r=0;r<4;r++){
      float rv = rs[r];
      rv += __shfl_xor(rv, 1, 64);
      rv += __shfl_xor(rv, 2, 64);
      rv += __shfl_xor(rv, 4, 64);
      rv += __shfl_xor(rv, 8, 64);
      l[r] = l[r]*sf[r] + rv;
    }
    s8v ap[2];
    ap[0] = *(const s8v*)&lsPw[fr*72 + fq*8];
    ap[1] = *(const s8v*)&lsPw[fr*72 + 32 + fq*8];
    #pragma unroll
    for (int kk=0;kk<2;kk++){
      #pragma unroll
      for (int n=0;n<4;n++){
        s8v bv = *(const s8v*)&lsVT[(16*n+fr)*72 + kk*32 + fq*8];
        out[n] = __builtin_amdgcn_mfma_f32_16x16x32_bf16(ap[kk], bv, out[n], 0,0,0);
      }
    }
  }
  float* pob = pout + ((long)(ck*BC*NH + bh))*64*64;
  #pragma unroll
  for (int n=0;n<4;n++)
    #pragma unroll
    for (int r=0;r<4;r++)
      pob[(w*16 + fq*4 + r)*64 + 16*n + fr] = out[n][r];
  if (fr == 0){
    float* pmb = pml + ((long)(ck*BC*NH + bh))*128;
    #pragma unroll
    for (int r=0;r<4;r++){
      pmb[(w*16 + fq*4 + r)*2 + 0] = m[r];
      pmb[(w*16 + fq*4 + r)*2 + 1] = l[r];
    }
  }
}

__global__ __launch_bounds__(256, 2)
void attn_global_combine(const float* __restrict__ pout, const float* __restrict__ pml,
                         u16* __restrict__ ctx)
{
  const int bh = blockIdx.x;
  const int b = bh / NH, h = bh % NH;
  const int t = threadIdx.x;
  __shared__ float wgt[KCH][64];
  __shared__ float rl[64];
  if (t < 64){
    float mc[KCH], lc[KCH];
    #pragma unroll
    for (int c = 0; c < KCH; c++){
      const float* pmb = pml + ((long)(c*BC*NH + bh))*128 + t*2;
      mc[c] = pmb[0]; lc[c] = pmb[1];
    }
    float M = mc[0];
    #pragma unroll
    for (int c = 1; c < KCH; c++) M = fmaxf(M, mc[c]);
    float L = 0.f;
    #pragma unroll
    for (int c = 0; c < KCH; c++){
      const float wv = exp2f(mc[c] - M);
      wgt[c][t] = wv;
      L += lc[c]*wv;
    }
    rl[t] = 1.f/L;
  }
  __syncthreads();
  const int row = t >> 2, dseg = t & 3;
  float acc[16];
  #pragma unroll
  for (int i=0;i<16;i++) acc[i] = 0.f;
  for (int c = 0; c < KCH; c++){
    const float wv = wgt[c][row];
    const float4* pb = (const float4*)(pout + ((long)(c*BC*NH + bh)*64 + row)*64 + dseg*16);
    #pragma unroll
    for (int i = 0; i < 4; i++){
      float4 v = pb[i];
      acc[i*4+0] += v.x*wv; acc[i*4+1] += v.y*wv;
      acc[i*4+2] += v.z*wv; acc[i*4+3] += v.w*wv;
    }
  }
  u16* cr = ctx + ((long)(b*SL + row))*DM + h*HD + dseg*16;
  const float r = rl[row];
  #pragma unroll
  for (int i = 0; i < 16; i += 2){
    u32 pk = (u32)f2b(acc[i]*r) | ((u32)f2b(acc[i+1]*r) << 16);
    *(u32*)(cr + i) = pk;
  }
}

// ---------------------------------------------------------------- LayerNorm + ans/span heads (fused)
__global__ __launch_bounds__(256, 2)
void ln_heads(const float* __restrict__ hbuf, const float* __restrict__ gamma, const float* __restrict__ beta,
              const float* __restrict__ Wa, const float* __restrict__ ba,
              const float* __restrict__ Wsp, const float* __restrict__ bsp,
              float* __restrict__ hn, float* __restrict__ ans, float* __restrict__ span)
{
  const int r = blockIdx.x;
  const int t = threadIdx.x, lane = t & 63, w = t >> 6;
  __shared__ float red[8];
  __shared__ float dred[4][5];
  const float* hrow = hbuf + (long)r*DM;
  float v0 = hrow[t], v1 = hrow[t+256], v2 = hrow[t+512];
  float sum = wredsum(v0 + v1 + v2);
  float sq  = wredsum(v0*v0 + v1*v1 + v2*v2);
  if (lane == 0){ red[w] = sum; red[4+w] = sq; }
  __syncthreads();
  const float mu  = (red[0]+red[1]+red[2]+red[3]) * (1.f/768.f);
  const float msq = (red[4]+red[5]+red[6]+red[7]) * (1.f/768.f);
  const float rstd = rsqrtf(msq - mu*mu + 1e-5f);
  float pa0=0,pa1=0,pa2=0,ps0=0,ps1=0;
  const long base = (long)r*DM;
  #pragma unroll
  for (int jj = 0; jj < 3; jj++){
    const int i = t + jj*256;
    const float hv = (jj==0) ? v0 : (jj==1) ? v1 : v2;
    const float y = (hv - mu)*rstd*gamma[i] + beta[i];
    hn[base + i] = y;
    pa0 += y*Wa[i*3+0]; pa1 += y*Wa[i*3+1]; pa2 += y*Wa[i*3+2];
    ps0 += y*Wsp[i*2+0]; ps1 += y*Wsp[i*2+1];
  }
  pa0 = wredsum(pa0); pa1 = wredsum(pa1); pa2 = wredsum(pa2);
  ps0 = wredsum(ps0); ps1 = wredsum(ps1);
  if (lane == 0){ dred[w][0]=pa0; dred[w][1]=pa1; dred[w][2]=pa2; dred[w][3]=ps0; dred[w][4]=ps1; }
  __syncthreads();
  if (t == 0){
    float A0 = dred[0][0]+dred[1][0]+dred[2][0]+dred[3][0];
    float A1 = dred[0][1]+dred[1][1]+dred[2][1]+dred[3][1];
    float A2 = dred[0][2]+dred[1][2]+dred[2][2]+dred[3][2];
    float S0 = dred[0][3]+dred[1][3]+dred[2][3]+dred[3][3];
    float S1 = dred[0][4]+dred[1][4]+dred[2][4]+dred[3][4];
    ans[(long)r*3+0]  = sigf(A0 + ba[0]);
    ans[(long)r*3+1]  = sigf(A1 + ba[1]);
    ans[(long)r*3+2]  = sigf(A2 + ba[2]);
    span[(long)r*2+0] = sigf(S0 + bsp[0]);
    span[(long)r*2+1] = sigf(S1 + bsp[1]);
  }
}

// ---------------------------------------------------------------- launch
extern "C" void kernel_launch(void* const* d_in, const int* in_sizes, int n_in,
                              void* d_out, int out_size, void* d_ws, size_t ws_size,
                              hipStream_t stream)
{
  const int*   input_ids = (const int*)  d_in[0];
  const float* attn_mask = (const float*)d_in[1];
  const int*   html_idx  = (const int*)  d_in[2];
  const float* embed     = (const float*)d_in[3];
  const float* Wq = (const float*)d_in[4];  const float* bq = (const float*)d_in[5];
  const float* Wk = (const float*)d_in[6];  const float* bk = (const float*)d_in[7];
  const float* Wv = (const float*)d_in[8];  const float* bv = (const float*)d_in[9];
  const float* Wo = (const float*)d_in[10]; const float* bo = (const float*)d_in[11];
  const float* gamma = (const float*)d_in[12]; const float* beta = (const float*)d_in[13];
  const float* Wp = (const float*)d_in[14]; const float* bp = (const float*)d_in[15];
  const float* Wa = (const float*)d_in[16]; const float* ba = (const float*)d_in[17];
  const float* Wsp = (const float*)d_in[18]; const float* bsp = (const float*)d_in[19];

  char* ws = (char*)d_ws;
  size_t off = 0;
  auto take = [&](size_t bytes)->char*{
    char* p = ws + off; off += (bytes + 255) & ~(size_t)255; return p;
  };
  float* x_f    = (float*)take((size_t)8192*768*4);
  u16*   x_b    = (u16*)  take((size_t)8192*768*2);
  u16*   wt_qkv = (u16*)  take((size_t)2304*768*2);
  u16*   wt_o   = (u16*)  take((size_t)768*768*2);
  u16*   wt_p   = (u16*)  take((size_t)768*768*2);
  float* b_qkv  = (float*)take(2304*4);
  u16*   qkv_b  = (u16*)  take((size_t)8192*2304*2);
  u16*   ctx_b  = (u16*)  take((size_t)8192*768*2);
  float* h_f    = (float*)take((size_t)8192*768*4);
  u16*   hr_b   = (u16*)  take((size_t)512*768*2);
  u16*   t_b    = (u16*)  take((size_t)512*768*2);
  float* pout   = (float*)take((size_t)KCH*BC*NH*64*64*4);
  float* pml    = (float*)take((size_t)KCH*BC*NH*128*4);

  float* out_hn   = (float*)d_out;
  float* out_ans  = out_hn  + (size_t)8192*768;
  float* out_span = out_ans + (size_t)8192*3;
  float* out_cond = out_span + (size_t)8192*2;

  transpose_pack<<<2304, 256, 0, stream>>>(Wq, wt_qkv,             768);
  transpose_pack<<<2304, 256, 0, stream>>>(Wk, wt_qkv +   768*768, 768);
  transpose_pack<<<2304, 256, 0, stream>>>(Wv, wt_qkv + 2*768*768, 768);
  transpose_pack<<<2304, 256, 0, stream>>>(Wo, wt_o, 768);
  transpose_pack<<<2304, 256, 0, stream>>>(Wp, wt_p, 768);
  pack_bias<<<9, 256, 0, stream>>>(bq, bk, bv, b_qkv);
  embed_gather<<<6144, 256, 0, stream>>>(input_ids, embed, x_f, x_b);

  gemm_bt<0><<<dim3(18,64,1), 256, 0, stream>>>(x_b, wt_qkv, b_qkv, nullptr,
                                                nullptr, qkv_b, 8192, 2304, 768, 0,0,0);
  attn_band_mfma<<<dim3(64,12,2), 256, 0, stream>>>(qkv_b, attn_mask, ctx_b);
  attn_global_part<<<dim3(KCH,12,2), 256, 0, stream>>>(qkv_b, attn_mask, pout, pml);
  attn_global_combine<<<BC*NH, 256, 0, stream>>>(pout, pml, ctx_b);
  gemm_bt<1><<<dim3(6,64,1), 256, 0, stream>>>(ctx_b, wt_o, bo, x_f,
                                               h_f, nullptr, 8192, 768, 768, 0,0,0);
  ln_heads<<<8192, 256, 0, stream>>>(h_f, gamma, beta, Wa, ba, Wsp, bsp,
                                     out_hn, out_ans, out_span);
  gather_hr<<<1536, 256, 0, stream>>>(html_idx, out_hn, hr_b);
  gemm_bt<2><<<dim3(6,4,1), 256, 0, stream>>>(hr_b, wt_p, bp, nullptr,
                                              nullptr, t_b, 512, 768, 768, 0,0,0);
  gemm_bt<3><<<dim3(2,2,2), 256, 0, stream>>>(t_b, hr_b, nullptr, nullptr,
                                              out_cond, nullptr, 256, 256, 768,
                                              (long)256*768, (long)256*768, (long)256*256);
}

// Round 4
// 234.499 us; speedup vs baseline: 4.9074x; 1.1228x over previous
//
#include <hip/hip_runtime.h>

typedef unsigned short u16;
typedef unsigned int   u32;
typedef __attribute__((ext_vector_type(8))) short s8v;           // MFMA bf16 frag (8 bf16)
typedef __attribute__((ext_vector_type(8))) unsigned short us8;  // raw bf16x8 load
typedef __attribute__((ext_vector_type(4))) float f4v;           // MFMA acc frag

constexpr int BC  = 2;
constexpr int SL  = 4096;
constexpr int NH  = 12;
constexpr int HD  = 64;
constexpr int DM  = 768;
constexpr int WIN = 256;
constexpr int GLB = 64;
constexpr int QN  = 2304;   // q|k|v packed columns
constexpr int KCH = 16;     // global-attn key chunks
constexpr float FOLD = 0.125f * 1.44269504088896f; // scale(1/sqrt(64)) * log2(e)
constexpr float NEGS = -1.0e9f;

__device__ __forceinline__ float b2f(u16 b){ return __uint_as_float(((u32)b) << 16); }
__device__ __forceinline__ u16 f2b(float f){
  u32 u = __float_as_uint(f);
  return (u16)((u + 0x7fffu + ((u >> 16) & 1u)) >> 16);  // RNE
}
__device__ __forceinline__ float wredsum(float v){
  #pragma unroll
  for (int o = 32; o > 0; o >>= 1) v += __shfl_xor(v, o, 64);
  return v;
}
__device__ __forceinline__ float sigf(float x){ return 1.f / (1.f + __expf(-x)); }

// ---------------------------------------------------------------- fused weight pack
// 5x 768x768 transposes (LDS-tiled, coalesced both sides) + qkv bias pack.
__global__ void pack_w(const float* __restrict__ Wq, const float* __restrict__ Wk,
                       const float* __restrict__ Wv, const float* __restrict__ Wo,
                       const float* __restrict__ Wp,
                       const float* __restrict__ bq, const float* __restrict__ bk,
                       const float* __restrict__ bv,
                       u16* __restrict__ wt_qkv, u16* __restrict__ wt_o,
                       u16* __restrict__ wt_p, float* __restrict__ b_qkv)
{
  __shared__ float tile[64][65];
  const int bid = blockIdx.x;                 // 720 = 5 * 144
  const int mi = bid / 144, rest = bid % 144;
  const int kt = rest / 12, ntc = rest % 12;
  const float* src = (mi==0)?Wq:(mi==1)?Wk:(mi==2)?Wv:(mi==3)?Wo:Wp;
  u16* dst = (mi<3) ? (wt_qkv + (size_t)mi*768*768) : ((mi==3) ? wt_o : wt_p);
  const int t = threadIdx.x;
  const int k0 = kt*64, n0 = ntc*64;
  #pragma unroll
  for (int i=0;i<4;i++){
    const int r = (t>>4) + i*16;
    float4 v = ((const float4*)(src + (long)(k0+r)*768 + n0))[t&15];
    tile[r][(t&15)*4+0] = v.x; tile[r][(t&15)*4+1] = v.y;
    tile[r][(t&15)*4+2] = v.z; tile[r][(t&15)*4+3] = v.w;
  }
  __syncthreads();
  const int n = t & 63, kc = (t>>6)*16;
  u32* d32 = (u32*)(dst + (long)(n0+n)*768 + k0 + kc);
  #pragma unroll
  for (int i=0;i<8;i++){
    d32[i] = (u32)f2b(tile[kc+2*i][n]) | ((u32)f2b(tile[kc+2*i+1][n]) << 16);
  }
  if (bid < 9){
    const int i = bid*256 + t;
    if (i < 2304) b_qkv[i] = (i < 768) ? bq[i] : (i < 1536) ? bk[i-768] : bv[i-1536];
  }
}

__global__ void embed_gather(const int* __restrict__ ids, const float* __restrict__ emb,
                             u16* __restrict__ xb){
  int e4 = blockIdx.x*256 + threadIdx.x;         // 8192 rows * 192 float4
  if (e4 >= 8192*192) return;
  int row = e4 / 192, d4 = e4 - row*192;
  int id = ids[row];
  float4 v = ((const float4*)(emb + (long)id*768))[d4];
  u32 p0 = (u32)f2b(v.x) | ((u32)f2b(v.y) << 16);
  u32 p1 = (u32)f2b(v.z) | ((u32)f2b(v.w) << 16);
  ((u32*)(xb + (long)row*768))[d4*2]   = p0;
  ((u32*)(xb + (long)row*768))[d4*2+1] = p1;
}

__global__ void gather_hr(const int* __restrict__ hidx, const float* __restrict__ hn,
                          u16* __restrict__ hrb){
  int e = blockIdx.x*256 + threadIdx.x;          // 512 rows * 768
  if (e >= 512*768) return;
  int r = e / 768, d = e - r*768;
  int b = r >> 8;
  int idx = hidx[r];
  hrb[e] = f2b(hn[((long)(b*SL + idx))*768 + d]);
}

// ---------------------------------------------------------------- bf16 MFMA GEMM
// MODE 0: outB = bf16(acc+bias)                 (qkv)
// MODE 1: outF = acc+bias+b2f(resB)             (h = x + ctx@Wo + bo, bf16 residual)
// MODE 2: outB = bf16(relu(acc+bias))           (t)
// MODE 3: outF = sigmoid(acc)                   (cond, batched)
template<int MODE>
__global__ __launch_bounds__(256, 2)
void gemm_bt(const u16* __restrict__ A, const u16* __restrict__ Bt,
             const float* __restrict__ bias, const u16* __restrict__ resB,
             float* __restrict__ outF, u16* __restrict__ outB,
             int M, int N, int K, long sA, long sB, long sO)
{
  const int bz = blockIdx.z;
  A  += (long)bz * sA;
  Bt += (long)bz * sB;
  const int n0 = blockIdx.x * 128;
  const int m0 = blockIdx.y * 128;
  __shared__ u16 lsA[128*64];
  __shared__ u16 lsB[128*64];
  const int t = threadIdx.x;
  const int w = t >> 6, lane = t & 63;
  const int wr = w >> 1, wc = w & 1;
  const int fr = lane & 15, fq = lane >> 4;

  f4v acc[4][4];
  #pragma unroll
  for (int i=0;i<4;i++)
    #pragma unroll
    for (int j=0;j<4;j++) acc[i][j] = (f4v)0.f;

  for (int k0 = 0; k0 < K; k0 += 64){
    #pragma unroll
    for (int i=0;i<4;i++){
      int e = (w*4+i)*512 + lane*8;
      int row = e >> 6, col = e & 63;
      __builtin_amdgcn_global_load_lds(
        (const __attribute__((address_space(1))) void*)(A + (long)(m0+row)*K + (k0+col)),
        (__attribute__((address_space(3))) void*)(&lsA[(w*4+i)*512]), 16, 0, 0);
      __builtin_amdgcn_global_load_lds(
        (const __attribute__((address_space(1))) void*)(Bt + (long)(n0+row)*K + (k0+col)),
        (__attribute__((address_space(3))) void*)(&lsB[(w*4+i)*512]), 16, 0, 0);
    }
    __syncthreads();
    #pragma unroll
    for (int kk = 0; kk < 2; kk++){
      s8v af[4], bfv[4];
      #pragma unroll
      for (int mi=0;mi<4;mi++)
        af[mi] = *(const s8v*)&lsA[(wr*64 + mi*16 + fr)*64 + kk*32 + fq*8];
      #pragma unroll
      for (int ni=0;ni<4;ni++)
        bfv[ni] = *(const s8v*)&lsB[(wc*64 + ni*16 + fr)*64 + kk*32 + fq*8];
      #pragma unroll
      for (int mi=0;mi<4;mi++)
        #pragma unroll
        for (int ni=0;ni<4;ni++)
          acc[mi][ni] = __builtin_amdgcn_mfma_f32_16x16x32_bf16(af[mi], bfv[ni], acc[mi][ni], 0, 0, 0);
    }
    __syncthreads();
  }
  #pragma unroll
  for (int mi=0;mi<4;mi++){
    #pragma unroll
    for (int ni=0;ni<4;ni++){
      #pragma unroll
      for (int r=0;r<4;r++){
        int row = m0 + wr*64 + mi*16 + fq*4 + r;
        int col = n0 + wc*64 + ni*16 + fr;
        float v = acc[mi][ni][r];
        if constexpr (MODE == 0){
          v += bias[col];
          outB[(long)row*N + col] = f2b(v);
        } else if constexpr (MODE == 1){
          v += bias[col] + b2f(resB[(long)row*N + col]);
          outF[(long)row*N + col] = v;
        } else if constexpr (MODE == 2){
          v = fmaxf(v + bias[col], 0.f);
          outB[(long)row*N + col] = f2b(v);
        } else {
          (outF + bz*sO)[(long)row*N + col] = sigf(v);
        }
      }
    }
  }
}

// ---------------------------------------------------------------- banded attention, MFMA flash, 2-phase pipelined
// Double-buffered K (DMA) / V (reg-staged, async-split) / mask. One barrier per tile:
//   [finish V writes -> barrier -> issue stage(i+1) -> compute(i)]
// Hazard proof: writes at iter i+2 to buffer p touch the buffer last READ in compute(i),
// and the barrier at iter i+1 separates them (all waves' compute(i) reads precede it).
__global__ __launch_bounds__(256, 3)
void attn_band_mfma(const u16* __restrict__ qkv, const float* __restrict__ mask, u16* __restrict__ ctx)
{
  const int q0 = blockIdx.x * 64;
  const int h = blockIdx.y, b = blockIdx.z;
  const int t = threadIdx.x;
  const int w = t >> 6, lane = t & 63;
  const int fq = lane >> 4, fr = lane & 15;

  __shared__ u16 lsK[2][64*64];    // row r: 16B chunk c8 holds K[r][(c8^(r&7))*8 ..+8)
  __shared__ u16 lsVT[2][64*72];   // V^T[d][k], row stride 72
  __shared__ u16 lsP[4][16*72];    // per-wave P (wave-local, no barrier needed)
  __shared__ float lsM[2][64];

  const long bq = (long)b*SL*QN;
  const u16* qrow = qkv + (bq + (long)(q0 + w*16 + fr)*QN) + h*HD;
  s8v aq[2];
  aq[0] = *(const s8v*)(qrow + fq*8);
  aq[1] = *(const s8v*)(qrow + 32 + fq*8);

  const u16* kq = qkv + bq + DM + h*HD;
  const u16* vq = qkv + bq + 2*DM + h*HD;
  const float* mrow = mask + b*SL;

  // dense tile list: i=0 -> global keys (k0=0); i>=1 -> band tiles (k0 in [64, SL))
  const int ti_lo = (q0 < 320) ? ((320 - q0) >> 6) : 0;
  const int ti_hi_raw = (4352 - q0) >> 6;
  const int ti_hi = ti_hi_raw < 9 ? ti_hi_raw : 9;
  const int NTT = 1 + (ti_hi - ti_lo);
  const int kb0 = q0 - 256 + ti_lo*64;

  f4v out[4];
  #pragma unroll
  for (int n=0;n<4;n++) out[n] = (f4v)0.f;
  float m[4]  = {-3.0e38f,-3.0e38f,-3.0e38f,-3.0e38f};
  float l[4]  = {0.f,0.f,0.f,0.f};

  us8 vv0, vv1;
  auto stage_issue = [&](int i, int buf){
    const int k0 = (i == 0) ? 0 : kb0 + (i-1)*64;
    if (t < 64) lsM[buf][t] = mrow[k0 + t];
    #pragma unroll
    for (int j=0;j<2;j++){
      const int r = (w*2+j)*8 + (lane>>3);
      const int d = ((lane&7) ^ (lane>>3))*8;          // pre-swizzled source col
      __builtin_amdgcn_global_load_lds(
        (const __attribute__((address_space(1))) void*)(kq + (long)(k0+r)*QN + d),
        (__attribute__((address_space(3))) void*)(&lsK[buf][(w*2+j)*512]), 16, 0, 0);
    }
    vv0 = *(const us8*)(vq + (long)(k0+lane)*QN + w*8);
    vv1 = *(const us8*)(vq + (long)(k0+lane)*QN + w*8 + 32);
  };

  stage_issue(0, 0);
  int cur = 0;
  for (int i = 0; i < NTT; i++){
    const int k0 = (i == 0) ? 0 : kb0 + (i-1)*64;
    // finish V staging for tile i (vmcnt wait on vv inserted by compiler)
    const int d0 = w*8;
    #pragma unroll
    for (int jj=0;jj<8;jj++) lsVT[cur][(d0+jj)*72 + lane] = (u16)vv0[jj];
    #pragma unroll
    for (int jj=0;jj<8;jj++) lsVT[cur][(d0+32+jj)*72 + lane] = (u16)vv1[jj];
    __syncthreads();                      // drains vmcnt(0): K-DMA(i) complete too
    if (i+1 < NTT) stage_issue(i+1, cur^1);

    // === compute tile i from buffers [cur] ===
    f4v s[4];
    #pragma unroll
    for (int n=0;n<4;n++) s[n] = (f4v)0.f;
    #pragma unroll
    for (int kk=0;kk<2;kk++){
      #pragma unroll
      for (int n=0;n<4;n++){
        s8v bf = *(const s8v*)&lsK[cur][(16*n+fr)*64 + (((kk*4+fq) ^ (fr&7))<<3)];
        s[n] = __builtin_amdgcn_mfma_f32_16x16x32_bf16(aq[kk], bf, s[n], 0,0,0);
      }
    }
    const bool isg = (i == 0);
    #pragma unroll
    for (int n=0;n<4;n++){
      const int kcol = 16*n + fr;
      const float mk = lsM[cur][kcol];
      #pragma unroll
      for (int r=0;r<4;r++){
        const int dd = k0 + kcol - (q0 + w*16 + fq*4 + r);
        const bool valid = (mk > 0.f) && (isg || (dd >= -WIN && dd <= WIN));
        s[n][r] = valid ? s[n][r]*FOLD : NEGS;
      }
    }
    float sf[4];
    #pragma unroll
    for (int r=0;r<4;r++){
      float rm = fmaxf(fmaxf(s[0][r], s[1][r]), fmaxf(s[2][r], s[3][r]));
      rm = fmaxf(rm, __shfl_xor(rm, 1, 64));
      rm = fmaxf(rm, __shfl_xor(rm, 2, 64));
      rm = fmaxf(rm, __shfl_xor(rm, 4, 64));
      rm = fmaxf(rm, __shfl_xor(rm, 8, 64));
      const float mn = fmaxf(m[r], rm);
      sf[r] = exp2f(m[r] - mn);
      m[r] = mn;
    }
    u16* lsPw = lsP[w];
    float rs[4] = {0.f,0.f,0.f,0.f};
    #pragma unroll
    for (int n=0;n<4;n++){
      #pragma unroll
      for (int r=0;r<4;r++){
        float p = exp2f(s[n][r] - m[r]);
        rs[r] += p;
        lsPw[(fq*4+r)*72 + 16*n + fr] = f2b(p);
        out[n][r] *= sf[r];
      }
    }
    #pragma unroll
    for (int r=0;r<4;r++){
      float rv = rs[r];
      rv += __shfl_xor(rv, 1, 64);
      rv += __shfl_xor(rv, 2, 64);
      rv += __shfl_xor(rv, 4, 64);
      rv += __shfl_xor(rv, 8, 64);
      l[r] = l[r]*sf[r] + rv;
    }
    s8v ap[2];
    ap[0] = *(const s8v*)&lsPw[fr*72 + fq*8];
    ap[1] = *(const s8v*)&lsPw[fr*72 + 32 + fq*8];
    #pragma unroll
    for (int kk=0;kk<2;kk++){
      #pragma unroll
      for (int n=0;n<4;n++){
        s8v bv = *(const s8v*)&lsVT[cur][(16*n+fr)*72 + kk*32 + fq*8];
        out[n] = __builtin_amdgcn_mfma_f32_16x16x32_bf16(ap[kk], bv, out[n], 0,0,0);
      }
    }
    cur ^= 1;
  }
  #pragma unroll
  for (int r=0;r<4;r++) l[r] = 1.f/l[r];
  u16* cb = ctx + (((long)(b*SL) + q0 + w*16 + fq*4))*DM + h*HD + fr;
  #pragma unroll
  for (int n=0;n<4;n++)
    #pragma unroll
    for (int r=0;r<4;r++)
      cb[(long)r*DM + 16*n] = f2b(out[n][r]*l[r]);
}

// ---------------------------------------------------------------- global rows, MFMA flash partials, 2-phase pipelined
__global__ __launch_bounds__(256, 3)
void attn_global_part(const u16* __restrict__ qkv, const float* __restrict__ mask,
                      float* __restrict__ pout, float* __restrict__ pml)
{
  const int ck = blockIdx.x;
  const int h = blockIdx.y, b = blockIdx.z;
  const int bh = b*NH + h;
  const int t = threadIdx.x;
  const int w = t >> 6, lane = t & 63;
  const int fq = lane >> 4, fr = lane & 15;

  __shared__ u16 lsK[2][64*64];
  __shared__ u16 lsVT[2][64*72];
  __shared__ u16 lsP[4][16*72];
  __shared__ float lsM[2][64];

  const long bq = (long)b*SL*QN;
  const u16* qrow = qkv + (bq + (long)(w*16 + fr)*QN) + h*HD;   // q rows 0..63
  s8v aq[2];
  aq[0] = *(const s8v*)(qrow + fq*8);
  aq[1] = *(const s8v*)(qrow + 32 + fq*8);

  const u16* kq = qkv + bq + DM + h*HD;
  const u16* vq = qkv + bq + 2*DM + h*HD;
  const float* mrow = mask + b*SL;

  f4v out[4];
  #pragma unroll
  for (int n=0;n<4;n++) out[n] = (f4v)0.f;
  float m[4]  = {-3.0e38f,-3.0e38f,-3.0e38f,-3.0e38f};
  float l[4]  = {0.f,0.f,0.f,0.f};

  us8 vv0, vv1;
  auto stage_issue = [&](int i, int buf){
    const int k0 = ck*256 + i*64;
    if (t < 64) lsM[buf][t] = mrow[k0 + t];
    #pragma unroll
    for (int j=0;j<2;j++){
      const int r = (w*2+j)*8 + (lane>>3);
      const int d = ((lane&7) ^ (lane>>3))*8;
      __builtin_amdgcn_global_load_lds(
        (const __attribute__((address_space(1))) void*)(kq + (long)(k0+r)*QN + d),
        (__attribute__((address_space(3))) void*)(&lsK[buf][(w*2+j)*512]), 16, 0, 0);
    }
    vv0 = *(const us8*)(vq + (long)(k0+lane)*QN + w*8);
    vv1 = *(const us8*)(vq + (long)(k0+lane)*QN + w*8 + 32);
  };

  stage_issue(0, 0);
  int cur = 0;
  for (int i = 0; i < 4; i++){
    const int d0 = w*8;
    #pragma unroll
    for (int jj=0;jj<8;jj++) lsVT[cur][(d0+jj)*72 + lane] = (u16)vv0[jj];
    #pragma unroll
    for (int jj=0;jj<8;jj++) lsVT[cur][(d0+32+jj)*72 + lane] = (u16)vv1[jj];
    __syncthreads();
    if (i+1 < 4) stage_issue(i+1, cur^1);

    f4v s[4];
    #pragma unroll
    for (int n=0;n<4;n++) s[n] = (f4v)0.f;
    #pragma unroll
    for (int kk=0;kk<2;kk++){
      #pragma unroll
      for (int n=0;n<4;n++){
        s8v bf = *(const s8v*)&lsK[cur][(16*n+fr)*64 + (((kk*4+fq) ^ (fr&7))<<3)];
        s[n] = __builtin_amdgcn_mfma_f32_16x16x32_bf16(aq[kk], bf, s[n], 0,0,0);
      }
    }
    #pragma unroll
    for (int n=0;n<4;n++){
      const float mk = lsM[cur][16*n + fr];
      #pragma unroll
      for (int r=0;r<4;r++)
        s[n][r] = (mk > 0.f) ? s[n][r]*FOLD : NEGS;
    }
    float sf[4];
    #pragma unroll
    for (int r=0;r<4;r++){
      float rm = fmaxf(fmaxf(s[0][r], s[1][r]), fmaxf(s[2][r], s[3][r]));
      rm = fmaxf(rm, __shfl_xor(rm, 1, 64));
      rm = fmaxf(rm, __shfl_xor(rm, 2, 64));
      rm = fmaxf(rm, __shfl_xor(rm, 4, 64));
      rm = fmaxf(rm, __shfl_xor(rm, 8, 64));
      const float mn = fmaxf(m[r], rm);
      sf[r] = exp2f(m[r] - mn);
      m[r] = mn;
    }
    u16* lsPw = lsP[w];
    float rs[4] = {0.f,0.f,0.f,0.f};
    #pragma unroll
    for (int n=0;n<4;n++){
      #pragma unroll
      for (int r=0;r<4;r++){
        float p = exp2f(s[n][r] - m[r]);
        rs[r] += p;
        lsPw[(fq*4+r)*72 + 16*n + fr] = f2b(p);
        out[n][r] *= sf[r];
      }
    }
    #pragma unroll
    for (int r=0;r<4;r++){
      float rv = rs[r];
      rv += __shfl_xor(rv, 1, 64);
      rv += __shfl_xor(rv, 2, 64);
      rv += __shfl_xor(rv, 4, 64);
      rv += __shfl_xor(rv, 8, 64);
      l[r] = l[r]*sf[r] + rv;
    }
    s8v ap[2];
    ap[0] = *(const s8v*)&lsPw[fr*72 + fq*8];
    ap[1] = *(const s8v*)&lsPw[fr*72 + 32 + fq*8];
    #pragma unroll
    for (int kk=0;kk<2;kk++){
      #pragma unroll
      for (int n=0;n<4;n++){
        s8v bv = *(const s8v*)&lsVT[cur][(16*n+fr)*72 + kk*32 + fq*8];
        out[n] = __builtin_amdgcn_mfma_f32_16x16x32_bf16(ap[kk], bv, out[n], 0,0,0);
      }
    }
    cur ^= 1;
  }
  float* pob = pout + ((long)(ck*BC*NH + bh))*64*64;
  #pragma unroll
  for (int n=0;n<4;n++)
    #pragma unroll
    for (int r=0;r<4;r++)
      pob[(w*16 + fq*4 + r)*64 + 16*n + fr] = out[n][r];
  if (fr == 0){
    float* pmb = pml + ((long)(ck*BC*NH + bh))*128;
    #pragma unroll
    for (int r=0;r<4;r++){
      pmb[(w*16 + fq*4 + r)*2 + 0] = m[r];
      pmb[(w*16 + fq*4 + r)*2 + 1] = l[r];
    }
  }
}

__global__ __launch_bounds__(256, 2)
void attn_global_combine(const float* __restrict__ pout, const float* __restrict__ pml,
                         u16* __restrict__ ctx)
{
  const int bh = blockIdx.x;
  const int b = bh / NH, h = bh % NH;
  const int t = threadIdx.x;
  __shared__ float wgt[KCH][64];
  __shared__ float rl[64];
  if (t < 64){
    float mc[KCH], lc[KCH];
    #pragma unroll
    for (int c = 0; c < KCH; c++){
      const float* pmb = pml + ((long)(c*BC*NH + bh))*128 + t*2;
      mc[c] = pmb[0]; lc[c] = pmb[1];
    }
    float M = mc[0];
    #pragma unroll
    for (int c = 1; c < KCH; c++) M = fmaxf(M, mc[c]);
    float L = 0.f;
    #pragma unroll
    for (int c = 0; c < KCH; c++){
      const float wv = exp2f(mc[c] - M);
      wgt[c][t] = wv;
      L += lc[c]*wv;
    }
    rl[t] = 1.f/L;
  }
  __syncthreads();
  const int row = t >> 2, dseg = t & 3;
  float acc[16];
  #pragma unroll
  for (int i=0;i<16;i++) acc[i] = 0.f;
  for (int c = 0; c < KCH; c++){
    const float wv = wgt[c][row];
    const float4* pb = (const float4*)(pout + ((long)(c*BC*NH + bh)*64 + row)*64 + dseg*16);
    #pragma unroll
    for (int i = 0; i < 4; i++){
      float4 v = pb[i];
      acc[i*4+0] += v.x*wv; acc[i*4+1] += v.y*wv;
      acc[i*4+2] += v.z*wv; acc[i*4+3] += v.w*wv;
    }
  }
  u16* cr = ctx + ((long)(b*SL + row))*DM + h*HD + dseg*16;
  const float r = rl[row];
  #pragma unroll
  for (int i = 0; i < 16; i += 2){
    u32 pk = (u32)f2b(acc[i]*r) | ((u32)f2b(acc[i+1]*r) << 16);
    *(u32*)(cr + i) = pk;
  }
}

// ---------------------------------------------------------------- LayerNorm + ans/span heads (fused)
__global__ __launch_bounds__(256, 2)
void ln_heads(const float* __restrict__ hbuf, const float* __restrict__ gamma, const float* __restrict__ beta,
              const float* __restrict__ Wa, const float* __restrict__ ba,
              const float* __restrict__ Wsp, const float* __restrict__ bsp,
              float* __restrict__ hn, float* __restrict__ ans, float* __restrict__ span)
{
  const int r = blockIdx.x;
  const int t = threadIdx.x, lane = t & 63, w = t >> 6;
  __shared__ float red[8];
  __shared__ float dred[4][5];
  const float* hrow = hbuf + (long)r*DM;
  float v0 = hrow[t], v1 = hrow[t+256], v2 = hrow[t+512];
  float sum = wredsum(v0 + v1 + v2);
  float sq  = wredsum(v0*v0 + v1*v1 + v2*v2);
  if (lane == 0){ red[w] = sum; red[4+w] = sq; }
  __syncthreads();
  const float mu  = (red[0]+red[1]+red[2]+red[3]) * (1.f/768.f);
  const float msq = (red[4]+red[5]+red[6]+red[7]) * (1.f/768.f);
  const float rstd = rsqrtf(msq - mu*mu + 1e-5f);
  float pa0=0,pa1=0,pa2=0,ps0=0,ps1=0;
  const long base = (long)r*DM;
  #pragma unroll
  for (int jj = 0; jj < 3; jj++){
    const int i = t + jj*256;
    const float hv = (jj==0) ? v0 : (jj==1) ? v1 : v2;
    const float y = (hv - mu)*rstd*gamma[i] + beta[i];
    hn[base + i] = y;
    pa0 += y*Wa[i*3+0]; pa1 += y*Wa[i*3+1]; pa2 += y*Wa[i*3+2];
    ps0 += y*Wsp[i*2+0]; ps1 += y*Wsp[i*2+1];
  }
  pa0 = wredsum(pa0); pa1 = wredsum(pa1); pa2 = wredsum(pa2);
  ps0 = wredsum(ps0); ps1 = wredsum(ps1);
  if (lane == 0){ dred[w][0]=pa0; dred[w][1]=pa1; dred[w][2]=pa2; dred[w][3]=ps0; dred[w][4]=ps1; }
  __syncthreads();
  if (t == 0){
    float A0 = dred[0][0]+dred[1][0]+dred[2][0]+dred[3][0];
    float A1 = dred[0][1]+dred[1][1]+dred[2][1]+dred[3][1];
    float A2 = dred[0][2]+dred[1][2]+dred[2][2]+dred[3][2];
    float S0 = dred[0][3]+dred[1][3]+dred[2][3]+dred[3][3];
    float S1 = dred[0][4]+dred[1][4]+dred[2][4]+dred[3][4];
    ans[(long)r*3+0]  = sigf(A0 + ba[0]);
    ans[(long)r*3+1]  = sigf(A1 + ba[1]);
    ans[(long)r*3+2]  = sigf(A2 + ba[2]);
    span[(long)r*2+0] = sigf(S0 + bsp[0]);
    span[(long)r*2+1] = sigf(S1 + bsp[1]);
  }
}

// ---------------------------------------------------------------- launch
extern "C" void kernel_launch(void* const* d_in, const int* in_sizes, int n_in,
                              void* d_out, int out_size, void* d_ws, size_t ws_size,
                              hipStream_t stream)
{
  const int*   input_ids = (const int*)  d_in[0];
  const float* attn_mask = (const float*)d_in[1];
  const int*   html_idx  = (const int*)  d_in[2];
  const float* embed     = (const float*)d_in[3];
  const float* Wq = (const float*)d_in[4];  const float* bq = (const float*)d_in[5];
  const float* Wk = (const float*)d_in[6];  const float* bk = (const float*)d_in[7];
  const float* Wv = (const float*)d_in[8];  const float* bv = (const float*)d_in[9];
  const float* Wo = (const float*)d_in[10]; const float* bo = (const float*)d_in[11];
  const float* gamma = (const float*)d_in[12]; const float* beta = (const float*)d_in[13];
  const float* Wp = (const float*)d_in[14]; const float* bp = (const float*)d_in[15];
  const float* Wa = (const float*)d_in[16]; const float* ba = (const float*)d_in[17];
  const float* Wsp = (const float*)d_in[18]; const float* bsp = (const float*)d_in[19];

  char* ws = (char*)d_ws;
  size_t off = 0;
  auto take = [&](size_t bytes)->char*{
    char* p = ws + off; off += (bytes + 255) & ~(size_t)255; return p;
  };
  u16*   x_b    = (u16*)  take((size_t)8192*768*2);
  u16*   wt_qkv = (u16*)  take((size_t)2304*768*2);
  u16*   wt_o   = (u16*)  take((size_t)768*768*2);
  u16*   wt_p   = (u16*)  take((size_t)768*768*2);
  float* b_qkv  = (float*)take(2304*4);
  u16*   qkv_b  = (u16*)  take((size_t)8192*2304*2);
  u16*   ctx_b  = (u16*)  take((size_t)8192*768*2);
  float* h_f    = (float*)take((size_t)8192*768*4);
  u16*   hr_b   = (u16*)  take((size_t)512*768*2);
  u16*   t_b    = (u16*)  take((size_t)512*768*2);
  float* pout   = (float*)take((size_t)KCH*BC*NH*64*64*4);
  float* pml    = (float*)take((size_t)KCH*BC*NH*128*4);

  float* out_hn   = (float*)d_out;
  float* out_ans  = out_hn  + (size_t)8192*768;
  float* out_span = out_ans + (size_t)8192*3;
  float* out_cond = out_span + (size_t)8192*2;

  pack_w<<<720, 256, 0, stream>>>(Wq, Wk, Wv, Wo, Wp, bq, bk, bv,
                                  wt_qkv, wt_o, wt_p, b_qkv);
  embed_gather<<<6144, 256, 0, stream>>>(input_ids, embed, x_b);

  gemm_bt<0><<<dim3(18,64,1), 256, 0, stream>>>(x_b, wt_qkv, b_qkv, nullptr,
                                                nullptr, qkv_b, 8192, 2304, 768, 0,0,0);
  attn_band_mfma<<<dim3(64,12,2), 256, 0, stream>>>(qkv_b, attn_mask, ctx_b);
  attn_global_part<<<dim3(KCH,12,2), 256, 0, stream>>>(qkv_b, attn_mask, pout, pml);
  attn_global_combine<<<BC*NH, 256, 0, stream>>>(pout, pml, ctx_b);
  gemm_bt<1><<<dim3(6,64,1), 256, 0, stream>>>(ctx_b, wt_o, bo, x_b,
                                               h_f, nullptr, 8192, 768, 768, 0,0,0);
  ln_heads<<<8192, 256, 0, stream>>>(h_f, gamma, beta, Wa, ba, Wsp, bsp,
                                     out_hn, out_ans, out_span);
  gather_hr<<<1536, 256, 0, stream>>>(html_idx, out_hn, hr_b);
  gemm_bt<2><<<dim3(6,4,1), 256, 0, stream>>>(hr_b, wt_p, bp, nullptr,
                                              nullptr, t_b, 512, 768, 768, 0,0,0);
  gemm_bt<3><<<dim3(2,2,2), 256, 0, stream>>>(t_b, hr_b, nullptr, nullptr,
                                              out_cond, nullptr, 256, 256, 768,
                                              (long)256*768, (long)256*768, (long)256*256);
}